// Round 1
// baseline (628.612 us; speedup 1.0000x reference)
//
#include <hip/hip_runtime.h>
#include <math.h>

// Problem constants
#define NB    2048
#define KK    64
#define MM    64
#define DD    256
#define NITER 15
#define MITER 3
#define IEPS  20.0f   // 1/0.05

typedef __bf16 bf16_t;
typedef bf16_t bf16x8 __attribute__((ext_vector_type(8)));
typedef bf16_t bf16x4 __attribute__((ext_vector_type(4)));
typedef float  f32x16 __attribute__((ext_vector_type(16)));

#define XSTR 264   // bf16 elems per LDS activation row (256 + 8 pad, keeps 16B align)
#define CSTR 65    // f32 elems per LDS C/T row (64 + 1 pad -> conflict-free col access)

// ---------------------------------------------------------------------------
// Prep: convert W1, W2 (fp32, [256][256] row-major, nn.Linear weight W[e][d])
// to bf16 in workspace. ws[0..65536) = W1, ws[65536..131072) = W2.
// ---------------------------------------------------------------------------
__global__ __launch_bounds__(256) void convert_w(const float* __restrict__ W1,
                                                 const float* __restrict__ W2,
                                                 bf16_t* __restrict__ wbf) {
    int i = blockIdx.x * 256 + threadIdx.x;   // grid 512 -> 131072 threads
    if (i < 65536) wbf[i] = (bf16_t)W1[i];
    else           wbf[i] = (bf16_t)W2[i - 65536];
}

// ---------------------------------------------------------------------------
// One MLP layer via MFMA 32x32x16 bf16.
//   out[n][e] = act( sum_d in[n][d] * W[e][d] + bias[e] )
// A-operand = W rows (A[m][k] = W[e0+m][d0+k]), B-operand = activation rows
// (B[k][n] = in[n0+n][d0+k]).  D tile is [32 e] x [32 n];
// C/D layout: n = lane&31, e_local = (reg&3) + 8*(reg>>2) + 4*(lane>>5).
// ---------------------------------------------------------------------------
__device__ __forceinline__ void mlp_layer(const bf16_t* __restrict__ in,
                                          const bf16_t* __restrict__ W,
                                          const float*  __restrict__ bias,
                                          bf16_t* __restrict__ outLds,
                                          bool relu, int ln, int wv) {
    const int l31 = ln & 31;
    const int lh  = ln >> 5;   // 0/1
    for (int etp = 0; etp < 2; ++etp) {
        const int e0 = (wv * 2 + etp) * 32;
        // Preload the 16 K-step A-fragments of W for this e-tile (global, L2-hot)
        bf16x8 af[16];
        const bf16_t* wrow = W + (size_t)(e0 + l31) * 256 + lh * 8;
        #pragma unroll
        for (int kc = 0; kc < 16; ++kc) af[kc] = *(const bf16x8*)(wrow + kc * 16);

        #pragma unroll
        for (int ntp = 0; ntp < 2; ++ntp) {
            const bf16_t* x0 = in + (size_t)(ntp * 64 + l31) * XSTR + lh * 8;
            const bf16_t* x1 = x0 + 32 * XSTR;
            f32x16 a[2];
            #pragma unroll
            for (int i = 0; i < 16; ++i) { a[0][i] = 0.0f; a[1][i] = 0.0f; }
            #pragma unroll
            for (int kc = 0; kc < 16; ++kc) {
                bf16x8 bx0 = *(const bf16x8*)(x0 + kc * 16);
                bf16x8 bx1 = *(const bf16x8*)(x1 + kc * 16);
                a[0] = __builtin_amdgcn_mfma_f32_32x32x16_bf16(af[kc], bx0, a[0], 0, 0, 0);
                a[1] = __builtin_amdgcn_mfma_f32_32x32x16_bf16(af[kc], bx1, a[1], 0, 0, 0);
            }
            #pragma unroll
            for (int z = 0; z < 2; ++z) {
                const int n = ntp * 64 + z * 32 + l31;
                #pragma unroll
                for (int g = 0; g < 4; ++g) {
                    const int e = e0 + 8 * g + 4 * lh;
                    bf16x4 p;
                    #pragma unroll
                    for (int rr = 0; rr < 4; ++rr) {
                        float v = a[z][4 * g + rr] + bias[e + rr];
                        if (relu) v = fmaxf(v, 0.0f);
                        p[rr] = (bf16_t)v;
                    }
                    *(bf16x4*)&outLds[(size_t)n * XSTR + e] = p;
                }
            }
        }
    }
}

// ---------------------------------------------------------------------------
// Fused kernel: one block per batch element.
// ---------------------------------------------------------------------------
__global__ __launch_bounds__(256, 1) void sinkhorn_fused(
    const float* __restrict__ sq, const float* __restrict__ sr,
    const float* __restrict__ mq, const float* __restrict__ mr,
    const float* __restrict__ b1, const float* __restrict__ b2,
    const bf16_t* __restrict__ wbf,
    float* __restrict__ out) {

    __shared__ bf16_t Xs[128 * XSTR];   // X, later F        (67584 B)
    __shared__ bf16_t Hs[128 * XSTR];   // h, later T (f32)  (67584 B)
    __shared__ float  Cs[64 * CSTR];    // C                 (16640 B)
    __shared__ float  nrm[128];
    __shared__ float  lmq_s[64], lmr_s[64], la_s[64], lb_s[64];
    __shared__ float  b1_s[256], b2_s[256];
    __shared__ float  red_s[4];

    const int b  = blockIdx.x;
    const int t  = threadIdx.x;
    const int ln = t & 63;
    const int wv = t >> 6;
    const int l31 = ln & 31;
    const int lh  = ln >> 5;

    // ---- Phase 0: load X = [sq_b ; sr_b], convert fp32 -> bf16 into LDS ----
    {
        const float4* sq4 = (const float4*)(sq + (size_t)b * KK * DD);
        const float4* sr4 = (const float4*)(sr + (size_t)b * MM * DD);
        for (int i = t; i < 8192; i += 256) {     // 8192 float4 = 128 rows * 64
            const int r  = i >> 6;                // wave-uniform row
            const int c4 = i & 63;
            float4 v = (r < 64) ? sq4[r * 64 + c4] : sr4[(r - 64) * 64 + c4];
            bf16x4 p;
            p[0] = (bf16_t)v.x; p[1] = (bf16_t)v.y;
            p[2] = (bf16_t)v.z; p[3] = (bf16_t)v.w;
            *(bf16x4*)&Xs[(size_t)r * XSTR + c4 * 4] = p;
        }
        b1_s[t] = b1[t];
        b2_s[t] = b2[t];
        if (t < 64)        lmq_s[t]       = __logf(fmaxf(mq[(size_t)b * 64 + t], 1e-8f));
        else if (t < 128)  lmr_s[t - 64]  = __logf(fmaxf(mr[(size_t)b * 64 + (t - 64)], 1e-8f));
        else if (t < 192)  lb_s[t - 128]  = 0.0f;
    }
    __syncthreads();

    // ---- Phase 1: h = relu(X @ W1^T + b1) ----
    mlp_layer(Xs, wbf, b1_s, Hs, true, ln, wv);
    __syncthreads();

    // ---- Phase 2: F = h @ W2^T + b2  (F overwrites Xs) ----
    mlp_layer(Hs, wbf + 65536, b2_s, Xs, false, ln, wv);
    __syncthreads();

    // ---- Phase 3: row norms ||f||^2 ----
    {
        const int r  = t >> 1;
        const int hf = t & 1;
        const bf16_t* frow = &Xs[(size_t)r * XSTR + hf * 128];
        float s = 0.0f;
        #pragma unroll
        for (int c = 0; c < 16; ++c) {
            bf16x8 v = *(const bf16x8*)(frow + c * 8);
            #pragma unroll
            for (int j2 = 0; j2 < 8; ++j2) { float f = (float)v[j2]; s = fmaf(f, f, s); }
        }
        s += __shfl_xor(s, 1);
        if (hf == 0) nrm[r] = s;
    }
    __syncthreads();

    // ---- Phase 4: cdist via MFMA; C -> LDS + global ----
    {
        const int qt = wv >> 1, rt = wv & 1;
        const bf16_t* qa = &Xs[(size_t)(qt * 32 + l31) * XSTR + lh * 8];
        const bf16_t* ra = &Xs[(size_t)(64 + rt * 32 + l31) * XSTR + lh * 8];
        f32x16 acc;
        #pragma unroll
        for (int i = 0; i < 16; ++i) acc[i] = 0.0f;
        #pragma unroll
        for (int kc = 0; kc < 16; ++kc) {
            bf16x8 av = *(const bf16x8*)(qa + kc * 16);
            bf16x8 bv = *(const bf16x8*)(ra + kc * 16);
            acc = __builtin_amdgcn_mfma_f32_32x32x16_bf16(av, bv, acc, 0, 0, 0);
        }
        float* outC = out + 2048 + (size_t)2048 * 4096 + (size_t)b * 4096;
        const int m = rt * 32 + l31;
        const float nr_m = nrm[64 + m];
        #pragma unroll
        for (int g = 0; g < 4; ++g) {
            #pragma unroll
            for (int rr = 0; rr < 4; ++rr) {
                const int q = qt * 32 + 8 * g + 4 * lh + rr;
                float d2 = nrm[q] + nr_m - 2.0f * acc[4 * g + rr];
                float cv = sqrtf(fmaxf(d2, 0.0f));
                Cs[q * CSTR + m] = cv;
                outC[q * 64 + m] = cv;
            }
        }
    }
    __syncthreads();

    // ---- Phase 5: Sinkhorn (C held in registers; la/lb in LDS) ----
    const int ki = t >> 2;     // row index k in pass A; column index m in pass B
    const int jj = t & 3;      // 16-element strip within the 64-vector
    float rowV[16], colV[16];
    #pragma unroll
    for (int i = 0; i < 16; ++i) {
        const int m2 = jj * 16 + i;
        rowV[i] = fmaf(Cs[ki * CSTR + m2], -IEPS, lmr_s[m2]);   // -C/eps + log mr[m]
        colV[i] = fmaf(Cs[m2 * CSTR + ki], -IEPS, lmq_s[m2]);   // -C/eps + log mq[k]
    }
    const float lmq_k = lmq_s[ki];
    const float lmr_m = lmr_s[ki];
    float vals[16];

    for (int it = 0; it < NITER; ++it) {
        // pass A: la[k] = -lse_m(lK + lb)
        float mx = -1e30f;
        #pragma unroll
        for (int i = 0; i < 16; ++i) {
            float v = rowV[i] + lb_s[jj * 16 + i];
            vals[i] = v; mx = fmaxf(mx, v);
        }
        mx = fmaxf(mx, __shfl_xor(mx, 1));
        mx = fmaxf(mx, __shfl_xor(mx, 2));
        float s = 0.0f;
        #pragma unroll
        for (int i = 0; i < 16; ++i) s += __expf(vals[i] - mx);
        s += __shfl_xor(s, 1);
        s += __shfl_xor(s, 2);
        if (jj == 0) la_s[ki] = -(lmq_k + mx + __logf(s));
        __syncthreads();

        // pass B: lb[m] = -lse_k(lK + la)
        mx = -1e30f;
        #pragma unroll
        for (int i = 0; i < 16; ++i) {
            float v = colV[i] + la_s[jj * 16 + i];
            vals[i] = v; mx = fmaxf(mx, v);
        }
        mx = fmaxf(mx, __shfl_xor(mx, 1));
        mx = fmaxf(mx, __shfl_xor(mx, 2));
        s = 0.0f;
        #pragma unroll
        for (int i = 0; i < 16; ++i) s += __expf(vals[i] - mx);
        s += __shfl_xor(s, 1);
        s += __shfl_xor(s, 2);
        if (jj == 0) lb_s[ki] = -(lmr_m + mx + __logf(s));
        __syncthreads();
    }

    // ---- Phase 6: T = exp(lK + la + lb), into LDS (overlaying Hs) ----
    float* Ts = (float*)Hs;
    {
        const float base = lmq_k + la_s[ki];
        #pragma unroll
        for (int i = 0; i < 16; ++i) {
            const int m2 = jj * 16 + i;
            Ts[ki * CSTR + m2] = __expf(rowV[i] + lb_s[m2] + base);
        }
    }
    __syncthreads();

    // ---- Phase 7: power iterations ----
    for (int pi = 0; pi < MITER; ++pi) {
        float vv[16], rs = 0.0f;
        #pragma unroll
        for (int i = 0; i < 16; ++i) {
            float v = Ts[ki * CSTR + jj * 16 + i];
            v = v * v; vv[i] = v; rs += v;
        }
        rs += __shfl_xor(rs, 1); rs += __shfl_xor(rs, 2);
        float inv = 1.0f / (rs + 1e-8f);
        #pragma unroll
        for (int i = 0; i < 16; ++i) Ts[ki * CSTR + jj * 16 + i] = vv[i] * inv;
        __syncthreads();

        float cs = 0.0f;
        #pragma unroll
        for (int i = 0; i < 16; ++i) { float v = Ts[(jj * 16 + i) * CSTR + ki]; vv[i] = v; cs += v; }
        cs += __shfl_xor(cs, 1); cs += __shfl_xor(cs, 2);
        inv = 1.0f / (cs + 1e-8f);
        #pragma unroll
        for (int i = 0; i < 16; ++i) Ts[(jj * 16 + i) * CSTR + ki] = vv[i] * inv;
        __syncthreads();
    }

    // ---- Phase 8: write T, compute c = sum(T*C), sig = sigmoid(-c) ----
    {
        float part = 0.0f;
        float tq[16];
        #pragma unroll
        for (int i = 0; i < 16; ++i) {
            const int m2 = jj * 16 + i;
            float tv = Ts[ki * CSTR + m2];
            tq[i] = tv;
            part = fmaf(tv, Cs[ki * CSTR + m2], part);
        }
        float* outT = out + 2048 + (size_t)b * 4096 + ki * 64 + jj * 16;
        #pragma unroll
        for (int q4 = 0; q4 < 4; ++q4) {
            float4 v = make_float4(tq[4 * q4], tq[4 * q4 + 1], tq[4 * q4 + 2], tq[4 * q4 + 3]);
            ((float4*)outT)[q4] = v;
        }
        #pragma unroll
        for (int off = 1; off < 64; off <<= 1) part += __shfl_xor(part, off);
        if (ln == 0) red_s[wv] = part;
    }
    __syncthreads();
    if (t == 0) {
        float c = red_s[0] + red_s[1] + red_s[2] + red_s[3];
        out[2048 + (size_t)2 * 2048 * 4096 + b] = c;          // c
        out[b] = 1.0f / (1.0f + __expf(c));                   // sigmoid(-c)
    }
}

extern "C" void kernel_launch(void* const* d_in, const int* in_sizes, int n_in,
                              void* d_out, int out_size, void* d_ws, size_t ws_size,
                              hipStream_t stream) {
    const float* sq = (const float*)d_in[0];
    const float* sr = (const float*)d_in[1];
    const float* mq = (const float*)d_in[2];
    const float* mr = (const float*)d_in[3];
    const float* W1 = (const float*)d_in[4];
    const float* b1 = (const float*)d_in[5];
    const float* W2 = (const float*)d_in[6];
    const float* b2 = (const float*)d_in[7];

    bf16_t* wbf = (bf16_t*)d_ws;   // 131072 bf16 = 256 KB

    convert_w<<<512, 256, 0, stream>>>(W1, W2, wbf);
    sinkhorn_fused<<<NB, 256, 0, stream>>>(sq, sr, mq, mr, b1, b2, wbf, (float*)d_out);
}

// Round 2
// 519.050 us; speedup vs baseline: 1.2111x; 1.2111x over previous
//
#include <hip/hip_runtime.h>
#include <math.h>

// Problem constants
#define NB    2048
#define KK    64
#define MM    64
#define DD    256
#define NITER 15
#define MITER 3
#define IEPS  20.0f   // 1/0.05

typedef __bf16 bf16_t;
typedef bf16_t bf16x8 __attribute__((ext_vector_type(8)));
typedef bf16_t bf16x4 __attribute__((ext_vector_type(4)));
typedef float  f32x16 __attribute__((ext_vector_type(16)));

#define XSTR 264   // bf16 elems per LDS activation row (256 + 8 pad, keeps 16B align)
#define CSTR 65    // f32 elems per LDS C/T row (64 + 1 pad -> conflict-free col access)

#define F_BYTES   134217728ull            // 262144 rows * 256 * 2B (bf16 f)
#define WBF_ELEMS 131072                  // W1+W2 bf16

// ---------------------------------------------------------------------------
// Prep: convert W1, W2 (fp32, [256][256] row-major) to bf16 at wbf.
// ---------------------------------------------------------------------------
__global__ __launch_bounds__(256) void convert_w(const float* __restrict__ W1,
                                                 const float* __restrict__ W2,
                                                 bf16_t* __restrict__ wbf) {
    int i = blockIdx.x * 256 + threadIdx.x;   // grid 512 -> 131072 threads
    if (i < 65536) wbf[i] = (bf16_t)W1[i];
    else           wbf[i] = (bf16_t)W2[i - 65536];
}

// ---------------------------------------------------------------------------
// One MLP layer over 64 rows via MFMA 32x32x16 bf16 (wave wv owns 64 e).
//   out[n][e] = act( sum_d in[n][d] * W[e][d] + bias[e] )
// A = W rows, B = activation rows. C/D: n = lane&31, e = (reg&3)+8*(reg>>2)+4*lh.
// ---------------------------------------------------------------------------
__device__ __forceinline__ void mlp_layer64(const bf16_t* __restrict__ in,
                                            const bf16_t* __restrict__ W,
                                            const float*  __restrict__ bias,
                                            bf16_t* __restrict__ outLds,
                                            bool relu, int l31, int lh, int wv) {
    #pragma unroll
    for (int etp = 0; etp < 2; ++etp) {
        const int e0 = (wv * 2 + etp) * 32;
        bf16x8 af[16];
        const bf16_t* wrow = W + (size_t)(e0 + l31) * 256 + lh * 8;
        #pragma unroll
        for (int kc = 0; kc < 16; ++kc) af[kc] = *(const bf16x8*)(wrow + kc * 16);

        const bf16_t* x0 = in + (size_t)l31 * XSTR + lh * 8;
        const bf16_t* x1 = x0 + 32 * XSTR;
        f32x16 a[2];
        #pragma unroll
        for (int i = 0; i < 16; ++i) { a[0][i] = 0.0f; a[1][i] = 0.0f; }
        #pragma unroll
        for (int kc = 0; kc < 16; ++kc) {
            bf16x8 bx0 = *(const bf16x8*)(x0 + kc * 16);
            bf16x8 bx1 = *(const bf16x8*)(x1 + kc * 16);
            a[0] = __builtin_amdgcn_mfma_f32_32x32x16_bf16(af[kc], bx0, a[0], 0, 0, 0);
            a[1] = __builtin_amdgcn_mfma_f32_32x32x16_bf16(af[kc], bx1, a[1], 0, 0, 0);
        }
        #pragma unroll
        for (int z = 0; z < 2; ++z) {
            const int n = z * 32 + l31;
            #pragma unroll
            for (int g = 0; g < 4; ++g) {
                const int e = e0 + 8 * g + 4 * lh;
                bf16x4 p;
                #pragma unroll
                for (int rr = 0; rr < 4; ++rr) {
                    float v = a[z][4 * g + rr] + bias[e + rr];
                    if (relu) v = fmaxf(v, 0.0f);
                    p[rr] = (bf16_t)v;
                }
                *(bf16x4*)&outLds[(size_t)n * XSTR + e] = p;
            }
        }
    }
}

// ---------------------------------------------------------------------------
// Kernel A: 2-layer MLP over 64 rows per block -> f (bf16) to workspace.
// Block bi: b = bi>>1, half = bi&1 (0 -> sq rows, 1 -> sr rows).
// f layout: row (b*128 + half*64 + r) * 256, bf16.
// LDS = 2 * 64*264*2 = 67.6 KB -> 2 blocks/CU.
// ---------------------------------------------------------------------------
__global__ __launch_bounds__(256, 2) void mlp_pair(
    const float* __restrict__ sq, const float* __restrict__ sr,
    const float* __restrict__ b1, const float* __restrict__ b2,
    const bf16_t* __restrict__ wbf, bf16_t* __restrict__ fout) {

    __shared__ bf16_t Xs[64 * XSTR];
    __shared__ bf16_t Hs[64 * XSTR];
    __shared__ float  b1_s[256], b2_s[256];

    const int bi = blockIdx.x;
    const int t  = threadIdx.x;
    const int ln = t & 63;
    const int wv = t >> 6;
    const int l31 = ln & 31;
    const int lh  = ln >> 5;

    const int b = bi >> 1, half = bi & 1;
    const float4* s4 = (const float4*)((half ? sr : sq) + (size_t)b * 64 * 256);

    #pragma unroll
    for (int it = 0; it < 16; ++it) {
        const int i  = t + it * 256;
        const int r  = i >> 6;      // wave-uniform row
        const int c4 = i & 63;
        float4 v = s4[i];
        bf16x4 p;
        p[0] = (bf16_t)v.x; p[1] = (bf16_t)v.y;
        p[2] = (bf16_t)v.z; p[3] = (bf16_t)v.w;
        *(bf16x4*)&Xs[(size_t)r * XSTR + c4 * 4] = p;
    }
    b1_s[t] = b1[t];
    b2_s[t] = b2[t];
    __syncthreads();

    mlp_layer64(Xs, wbf, b1_s, Hs, true, l31, lh, wv);
    __syncthreads();
    mlp_layer64(Hs, wbf + 65536, b2_s, Xs, false, l31, lh, wv);
    __syncthreads();

    bf16_t* fg = fout + (size_t)bi * 64 * 256;
    #pragma unroll
    for (int it = 0; it < 8; ++it) {
        const int i = t + it * 256;
        const int r = i >> 5;
        const int c = i & 31;
        bf16x8 v = *(const bf16x8*)&Xs[(size_t)r * XSTR + c * 8];
        *(bf16x8*)&fg[(size_t)r * 256 + c * 8] = v;
    }
}

// ---------------------------------------------------------------------------
// Kernel B: per-batch cdist + Sinkhorn + power iters + outputs.
// LDS: Fs (67.6 KB) overlaid after cdist by Cs (16.6 KB) + Ts (16.6 KB).
// -> 2 blocks/CU.
// ---------------------------------------------------------------------------
__global__ __launch_bounds__(256, 2) void sinkhorn_ot(
    const bf16_t* __restrict__ fg,
    const float* __restrict__ mq, const float* __restrict__ mr,
    float* __restrict__ out) {

    __shared__ __align__(16) char smem[128 * XSTR * 2];   // 67584 B
    bf16_t* Fs = (bf16_t*)smem;
    float*  Cs = (float*)smem;                     // [0, 16640)
    float*  Ts = (float*)(smem + 64 * CSTR * 4);   // [16640, 33280)
    __shared__ float nrm[128];
    __shared__ float lmq_s[64], lmr_s[64], la_s[64], lb_s[64];
    __shared__ float red_s[4];

    const int b  = blockIdx.x;
    const int t  = threadIdx.x;
    const int ln = t & 63;
    const int wv = t >> 6;
    const int l31 = ln & 31;
    const int lh  = ln >> 5;

    // ---- Stage f (128 rows x 256 bf16, coalesced) ----
    {
        const bf16_t* fb = fg + (size_t)b * 128 * 256;
        #pragma unroll
        for (int it = 0; it < 16; ++it) {
            const int i = t + it * 256;
            const int r = i >> 5;
            const int c = i & 31;
            bf16x8 v = *(const bf16x8*)&fb[(size_t)r * 256 + c * 8];
            *(bf16x8*)&Fs[(size_t)r * XSTR + c * 8] = v;
        }
        if (t < 64)        lmq_s[t]      = __logf(fmaxf(mq[(size_t)b * 64 + t], 1e-8f));
        else if (t < 128)  lmr_s[t - 64] = __logf(fmaxf(mr[(size_t)b * 64 + (t - 64)], 1e-8f));
        else if (t < 192)  lb_s[t - 128] = 0.0f;
    }
    __syncthreads();

    // ---- Row norms ||f||^2 ----
    {
        const int r  = t >> 1;
        const int hf = t & 1;
        const bf16_t* frow = &Fs[(size_t)r * XSTR + hf * 128];
        float s = 0.0f;
        #pragma unroll
        for (int c = 0; c < 16; ++c) {
            bf16x8 v = *(const bf16x8*)(frow + c * 8);
            #pragma unroll
            for (int j2 = 0; j2 < 8; ++j2) { float f = (float)v[j2]; s = fmaf(f, f, s); }
        }
        s += __shfl_xor(s, 1);
        if (hf == 0) nrm[r] = s;
    }
    __syncthreads();

    // ---- cdist via MFMA; C -> regs + global, then (after Fs dead) -> LDS ----
    float cvv[16];
    int   qbase, mcol;
    {
        const int qt = wv >> 1, rt = wv & 1;
        const bf16_t* qa = &Fs[(size_t)(qt * 32 + l31) * XSTR + lh * 8];
        const bf16_t* ra = &Fs[(size_t)(64 + rt * 32 + l31) * XSTR + lh * 8];
        f32x16 acc;
        #pragma unroll
        for (int i = 0; i < 16; ++i) acc[i] = 0.0f;
        #pragma unroll
        for (int kc = 0; kc < 16; ++kc) {
            bf16x8 av = *(const bf16x8*)(qa + kc * 16);
            bf16x8 bv = *(const bf16x8*)(ra + kc * 16);
            acc = __builtin_amdgcn_mfma_f32_32x32x16_bf16(av, bv, acc, 0, 0, 0);
        }
        float* outC = out + 2048 + (size_t)2048 * 4096 + (size_t)b * 4096;
        mcol = rt * 32 + l31;
        qbase = qt * 32;
        const float nr_m = nrm[64 + mcol];
        #pragma unroll
        for (int g = 0; g < 4; ++g) {
            #pragma unroll
            for (int rr = 0; rr < 4; ++rr) {
                const int q = qbase + 8 * g + 4 * lh + rr;
                float d2 = nrm[q] + nr_m - 2.0f * acc[4 * g + rr];
                float cv = sqrtf(fmaxf(d2, 0.0f));
                cvv[4 * g + rr] = cv;
                outC[q * 64 + mcol] = cv;
            }
        }
    }
    __syncthreads();   // Fs dead; safe to overlay Cs
    {
        #pragma unroll
        for (int g = 0; g < 4; ++g) {
            #pragma unroll
            for (int rr = 0; rr < 4; ++rr) {
                const int q = qbase + 8 * g + 4 * lh + rr;
                Cs[q * CSTR + mcol] = cvv[4 * g + rr];
            }
        }
    }
    __syncthreads();

    // ---- Sinkhorn (C rows/cols in registers; la/lb in LDS) ----
    const int ki = t >> 2;
    const int jj = t & 3;
    float rowV[16], colV[16];
    #pragma unroll
    for (int i = 0; i < 16; ++i) {
        const int m2 = jj * 16 + i;
        rowV[i] = fmaf(Cs[ki * CSTR + m2], -IEPS, lmr_s[m2]);
        colV[i] = fmaf(Cs[m2 * CSTR + ki], -IEPS, lmq_s[m2]);
    }
    const float lmq_k = lmq_s[ki];
    const float lmr_m = lmr_s[ki];
    float vals[16];

    for (int it = 0; it < NITER; ++it) {
        float mx = -1e30f;
        #pragma unroll
        for (int i = 0; i < 16; ++i) {
            float v = rowV[i] + lb_s[jj * 16 + i];
            vals[i] = v; mx = fmaxf(mx, v);
        }
        mx = fmaxf(mx, __shfl_xor(mx, 1));
        mx = fmaxf(mx, __shfl_xor(mx, 2));
        float s = 0.0f;
        #pragma unroll
        for (int i = 0; i < 16; ++i) s += __expf(vals[i] - mx);
        s += __shfl_xor(s, 1);
        s += __shfl_xor(s, 2);
        if (jj == 0) la_s[ki] = -(lmq_k + mx + __logf(s));
        __syncthreads();

        mx = -1e30f;
        #pragma unroll
        for (int i = 0; i < 16; ++i) {
            float v = colV[i] + la_s[jj * 16 + i];
            vals[i] = v; mx = fmaxf(mx, v);
        }
        mx = fmaxf(mx, __shfl_xor(mx, 1));
        mx = fmaxf(mx, __shfl_xor(mx, 2));
        s = 0.0f;
        #pragma unroll
        for (int i = 0; i < 16; ++i) s += __expf(vals[i] - mx);
        s += __shfl_xor(s, 1);
        s += __shfl_xor(s, 2);
        if (jj == 0) lb_s[ki] = -(lmr_m + mx + __logf(s));
        __syncthreads();
    }

    // ---- T = exp(lK + la + lb) ----
    {
        const float base = lmq_k + la_s[ki];
        #pragma unroll
        for (int i = 0; i < 16; ++i) {
            const int m2 = jj * 16 + i;
            Ts[ki * CSTR + m2] = __expf(rowV[i] + lb_s[m2] + base);
        }
    }
    __syncthreads();

    // ---- Power iterations ----
    for (int pi = 0; pi < MITER; ++pi) {
        float vv[16], rs = 0.0f;
        #pragma unroll
        for (int i = 0; i < 16; ++i) {
            float v = Ts[ki * CSTR + jj * 16 + i];
            v = v * v; vv[i] = v; rs += v;
        }
        rs += __shfl_xor(rs, 1); rs += __shfl_xor(rs, 2);
        float inv = 1.0f / (rs + 1e-8f);
        #pragma unroll
        for (int i = 0; i < 16; ++i) Ts[ki * CSTR + jj * 16 + i] = vv[i] * inv;
        __syncthreads();

        float cs = 0.0f;
        #pragma unroll
        for (int i = 0; i < 16; ++i) { float v = Ts[(jj * 16 + i) * CSTR + ki]; vv[i] = v; cs += v; }
        cs += __shfl_xor(cs, 1); cs += __shfl_xor(cs, 2);
        inv = 1.0f / (cs + 1e-8f);
        #pragma unroll
        for (int i = 0; i < 16; ++i) Ts[(jj * 16 + i) * CSTR + ki] = vv[i] * inv;
        __syncthreads();
    }

    // ---- Write T, c = sum(T*C), sigmoid(-c) ----
    {
        float part = 0.0f;
        float tq[16];
        #pragma unroll
        for (int i = 0; i < 16; ++i) {
            const int m2 = jj * 16 + i;
            float tv = Ts[ki * CSTR + m2];
            tq[i] = tv;
            part = fmaf(tv, Cs[ki * CSTR + m2], part);
        }
        float* outT = out + 2048 + (size_t)b * 4096 + ki * 64 + jj * 16;
        #pragma unroll
        for (int q4 = 0; q4 < 4; ++q4) {
            ((float4*)outT)[q4] = make_float4(tq[4 * q4], tq[4 * q4 + 1],
                                              tq[4 * q4 + 2], tq[4 * q4 + 3]);
        }
        #pragma unroll
        for (int off = 1; off < 64; off <<= 1) part += __shfl_xor(part, off);
        if (ln == 0) red_s[wv] = part;
    }
    __syncthreads();
    if (t == 0) {
        float c = red_s[0] + red_s[1] + red_s[2] + red_s[3];
        out[2048 + (size_t)2 * 2048 * 4096 + b] = c;
        out[b] = 1.0f / (1.0f + __expf(c));
    }
}

// ===========================================================================
// Fallback: round-1 fused kernel (used only if ws_size too small for f).
// ===========================================================================
__device__ __forceinline__ void mlp_layer128(const bf16_t* __restrict__ in,
                                             const bf16_t* __restrict__ W,
                                             const float*  __restrict__ bias,
                                             bf16_t* __restrict__ outLds,
                                             bool relu, int ln, int wv) {
    const int l31 = ln & 31;
    const int lh  = ln >> 5;
    for (int etp = 0; etp < 2; ++etp) {
        const int e0 = (wv * 2 + etp) * 32;
        bf16x8 af[16];
        const bf16_t* wrow = W + (size_t)(e0 + l31) * 256 + lh * 8;
        #pragma unroll
        for (int kc = 0; kc < 16; ++kc) af[kc] = *(const bf16x8*)(wrow + kc * 16);
        #pragma unroll
        for (int ntp = 0; ntp < 2; ++ntp) {
            const bf16_t* x0 = in + (size_t)(ntp * 64 + l31) * XSTR + lh * 8;
            const bf16_t* x1 = x0 + 32 * XSTR;
            f32x16 a[2];
            #pragma unroll
            for (int i = 0; i < 16; ++i) { a[0][i] = 0.0f; a[1][i] = 0.0f; }
            #pragma unroll
            for (int kc = 0; kc < 16; ++kc) {
                bf16x8 bx0 = *(const bf16x8*)(x0 + kc * 16);
                bf16x8 bx1 = *(const bf16x8*)(x1 + kc * 16);
                a[0] = __builtin_amdgcn_mfma_f32_32x32x16_bf16(af[kc], bx0, a[0], 0, 0, 0);
                a[1] = __builtin_amdgcn_mfma_f32_32x32x16_bf16(af[kc], bx1, a[1], 0, 0, 0);
            }
            #pragma unroll
            for (int z = 0; z < 2; ++z) {
                const int n = ntp * 64 + z * 32 + l31;
                #pragma unroll
                for (int g = 0; g < 4; ++g) {
                    const int e = e0 + 8 * g + 4 * lh;
                    bf16x4 p;
                    #pragma unroll
                    for (int rr = 0; rr < 4; ++rr) {
                        float v = a[z][4 * g + rr] + bias[e + rr];
                        if (relu) v = fmaxf(v, 0.0f);
                        p[rr] = (bf16_t)v;
                    }
                    *(bf16x4*)&outLds[(size_t)n * XSTR + e] = p;
                }
            }
        }
    }
}

__global__ __launch_bounds__(256, 1) void sinkhorn_fused(
    const float* __restrict__ sq, const float* __restrict__ sr,
    const float* __restrict__ mq, const float* __restrict__ mr,
    const float* __restrict__ b1, const float* __restrict__ b2,
    const bf16_t* __restrict__ wbf,
    float* __restrict__ out) {

    __shared__ bf16_t Xs[128 * XSTR];
    __shared__ bf16_t Hs[128 * XSTR];
    __shared__ float  Cs[64 * CSTR];
    __shared__ float  nrm[128];
    __shared__ float  lmq_s[64], lmr_s[64], la_s[64], lb_s[64];
    __shared__ float  b1_s[256], b2_s[256];
    __shared__ float  red_s[4];

    const int b  = blockIdx.x;
    const int t  = threadIdx.x;
    const int ln = t & 63;
    const int wv = t >> 6;
    const int l31 = ln & 31;
    const int lh  = ln >> 5;

    {
        const float4* sq4 = (const float4*)(sq + (size_t)b * KK * DD);
        const float4* sr4 = (const float4*)(sr + (size_t)b * MM * DD);
        for (int i = t; i < 8192; i += 256) {
            const int r  = i >> 6;
            const int c4 = i & 63;
            float4 v = (r < 64) ? sq4[r * 64 + c4] : sr4[(r - 64) * 64 + c4];
            bf16x4 p;
            p[0] = (bf16_t)v.x; p[1] = (bf16_t)v.y;
            p[2] = (bf16_t)v.z; p[3] = (bf16_t)v.w;
            *(bf16x4*)&Xs[(size_t)r * XSTR + c4 * 4] = p;
        }
        b1_s[t] = b1[t];
        b2_s[t] = b2[t];
        if (t < 64)        lmq_s[t]       = __logf(fmaxf(mq[(size_t)b * 64 + t], 1e-8f));
        else if (t < 128)  lmr_s[t - 64]  = __logf(fmaxf(mr[(size_t)b * 64 + (t - 64)], 1e-8f));
        else if (t < 192)  lb_s[t - 128]  = 0.0f;
    }
    __syncthreads();
    mlp_layer128(Xs, wbf, b1_s, Hs, true, ln, wv);
    __syncthreads();
    mlp_layer128(Hs, wbf + 65536, b2_s, Xs, false, ln, wv);
    __syncthreads();
    {
        const int r  = t >> 1;
        const int hf = t & 1;
        const bf16_t* frow = &Xs[(size_t)r * XSTR + hf * 128];
        float s = 0.0f;
        #pragma unroll
        for (int c = 0; c < 16; ++c) {
            bf16x8 v = *(const bf16x8*)(frow + c * 8);
            #pragma unroll
            for (int j2 = 0; j2 < 8; ++j2) { float f = (float)v[j2]; s = fmaf(f, f, s); }
        }
        s += __shfl_xor(s, 1);
        if (hf == 0) nrm[r] = s;
    }
    __syncthreads();
    {
        const int qt = wv >> 1, rt = wv & 1;
        const bf16_t* qa = &Xs[(size_t)(qt * 32 + l31) * XSTR + lh * 8];
        const bf16_t* ra = &Xs[(size_t)(64 + rt * 32 + l31) * XSTR + lh * 8];
        f32x16 acc;
        #pragma unroll
        for (int i = 0; i < 16; ++i) acc[i] = 0.0f;
        #pragma unroll
        for (int kc = 0; kc < 16; ++kc) {
            bf16x8 av = *(const bf16x8*)(qa + kc * 16);
            bf16x8 bv = *(const bf16x8*)(ra + kc * 16);
            acc = __builtin_amdgcn_mfma_f32_32x32x16_bf16(av, bv, acc, 0, 0, 0);
        }
        float* outC = out + 2048 + (size_t)2048 * 4096 + (size_t)b * 4096;
        const int m = rt * 32 + l31;
        const float nr_m = nrm[64 + m];
        #pragma unroll
        for (int g = 0; g < 4; ++g) {
            #pragma unroll
            for (int rr = 0; rr < 4; ++rr) {
                const int q = qt * 32 + 8 * g + 4 * lh + rr;
                float d2 = nrm[q] + nr_m - 2.0f * acc[4 * g + rr];
                float cv = sqrtf(fmaxf(d2, 0.0f));
                Cs[q * CSTR + m] = cv;
                outC[q * 64 + m] = cv;
            }
        }
    }
    __syncthreads();

    const int ki = t >> 2;
    const int jj = t & 3;
    float rowV[16], colV[16];
    #pragma unroll
    for (int i = 0; i < 16; ++i) {
        const int m2 = jj * 16 + i;
        rowV[i] = fmaf(Cs[ki * CSTR + m2], -IEPS, lmr_s[m2]);
        colV[i] = fmaf(Cs[m2 * CSTR + ki], -IEPS, lmq_s[m2]);
    }
    const float lmq_k = lmq_s[ki];
    const float lmr_m = lmr_s[ki];
    float vals[16];

    for (int it = 0; it < NITER; ++it) {
        float mx = -1e30f;
        #pragma unroll
        for (int i = 0; i < 16; ++i) {
            float v = rowV[i] + lb_s[jj * 16 + i];
            vals[i] = v; mx = fmaxf(mx, v);
        }
        mx = fmaxf(mx, __shfl_xor(mx, 1));
        mx = fmaxf(mx, __shfl_xor(mx, 2));
        float s = 0.0f;
        #pragma unroll
        for (int i = 0; i < 16; ++i) s += __expf(vals[i] - mx);
        s += __shfl_xor(s, 1);
        s += __shfl_xor(s, 2);
        if (jj == 0) la_s[ki] = -(lmq_k + mx + __logf(s));
        __syncthreads();

        mx = -1e30f;
        #pragma unroll
        for (int i = 0; i < 16; ++i) {
            float v = colV[i] + la_s[jj * 16 + i];
            vals[i] = v; mx = fmaxf(mx, v);
        }
        mx = fmaxf(mx, __shfl_xor(mx, 1));
        mx = fmaxf(mx, __shfl_xor(mx, 2));
        s = 0.0f;
        #pragma unroll
        for (int i = 0; i < 16; ++i) s += __expf(vals[i] - mx);
        s += __shfl_xor(s, 1);
        s += __shfl_xor(s, 2);
        if (jj == 0) lb_s[ki] = -(lmr_m + mx + __logf(s));
        __syncthreads();
    }

    float* Ts = (float*)Hs;
    {
        const float base = lmq_k + la_s[ki];
        #pragma unroll
        for (int i = 0; i < 16; ++i) {
            const int m2 = jj * 16 + i;
            Ts[ki * CSTR + m2] = __expf(rowV[i] + lb_s[m2] + base);
        }
    }
    __syncthreads();

    for (int pi = 0; pi < MITER; ++pi) {
        float vv[16], rs = 0.0f;
        #pragma unroll
        for (int i = 0; i < 16; ++i) {
            float v = Ts[ki * CSTR + jj * 16 + i];
            v = v * v; vv[i] = v; rs += v;
        }
        rs += __shfl_xor(rs, 1); rs += __shfl_xor(rs, 2);
        float inv = 1.0f / (rs + 1e-8f);
        #pragma unroll
        for (int i = 0; i < 16; ++i) Ts[ki * CSTR + jj * 16 + i] = vv[i] * inv;
        __syncthreads();

        float cs = 0.0f;
        #pragma unroll
        for (int i = 0; i < 16; ++i) { float v = Ts[(jj * 16 + i) * CSTR + ki]; vv[i] = v; cs += v; }
        cs += __shfl_xor(cs, 1); cs += __shfl_xor(cs, 2);
        inv = 1.0f / (cs + 1e-8f);
        #pragma unroll
        for (int i = 0; i < 16; ++i) Ts[(jj * 16 + i) * CSTR + ki] = vv[i] * inv;
        __syncthreads();
    }

    {
        float part = 0.0f;
        float tq[16];
        #pragma unroll
        for (int i = 0; i < 16; ++i) {
            const int m2 = jj * 16 + i;
            float tv = Ts[ki * CSTR + m2];
            tq[i] = tv;
            part = fmaf(tv, Cs[ki * CSTR + m2], part);
        }
        float* outT = out + 2048 + (size_t)b * 4096 + ki * 64 + jj * 16;
        #pragma unroll
        for (int q4 = 0; q4 < 4; ++q4) {
            ((float4*)outT)[q4] = make_float4(tq[4 * q4], tq[4 * q4 + 1],
                                              tq[4 * q4 + 2], tq[4 * q4 + 3]);
        }
        #pragma unroll
        for (int off = 1; off < 64; off <<= 1) part += __shfl_xor(part, off);
        if (ln == 0) red_s[wv] = part;
    }
    __syncthreads();
    if (t == 0) {
        float c = red_s[0] + red_s[1] + red_s[2] + red_s[3];
        out[2048 + (size_t)2 * 2048 * 4096 + b] = c;
        out[b] = 1.0f / (1.0f + __expf(c));
    }
}

extern "C" void kernel_launch(void* const* d_in, const int* in_sizes, int n_in,
                              void* d_out, int out_size, void* d_ws, size_t ws_size,
                              hipStream_t stream) {
    const float* sq = (const float*)d_in[0];
    const float* sr = (const float*)d_in[1];
    const float* mq = (const float*)d_in[2];
    const float* mr = (const float*)d_in[3];
    const float* W1 = (const float*)d_in[4];
    const float* b1 = (const float*)d_in[5];
    const float* W2 = (const float*)d_in[6];
    const float* b2 = (const float*)d_in[7];

    const size_t need = F_BYTES + (size_t)WBF_ELEMS * 2;
    if (ws_size >= need) {
        bf16_t* fbuf = (bf16_t*)d_ws;
        bf16_t* wbf  = (bf16_t*)((char*)d_ws + F_BYTES);
        convert_w<<<512, 256, 0, stream>>>(W1, W2, wbf);
        mlp_pair<<<4096, 256, 0, stream>>>(sq, sr, b1, b2, wbf, fbuf);
        sinkhorn_ot<<<NB, 256, 0, stream>>>(fbuf, mq, mr, (float*)d_out);
    } else {
        bf16_t* wbf = (bf16_t*)d_ws;
        convert_w<<<512, 256, 0, stream>>>(W1, W2, wbf);
        sinkhorn_fused<<<NB, 256, 0, stream>>>(sq, sr, mq, mr, b1, b2, wbf, (float*)d_out);
    }
}

// Round 3
// 502.167 us; speedup vs baseline: 1.2518x; 1.0336x over previous
//
#include <hip/hip_runtime.h>
#include <math.h>

// Problem constants
#define NB    2048
#define KK    64
#define MM    64
#define DD    256
#define NITER 15
#define MITER 3
#define IEPS  20.0f   // 1/0.05

typedef __bf16 bf16_t;
typedef bf16_t bf16x8 __attribute__((ext_vector_type(8)));
typedef bf16_t bf16x4 __attribute__((ext_vector_type(4)));
typedef float  f32x16 __attribute__((ext_vector_type(16)));

#define XSTR 264   // bf16 elems per LDS activation row (256 + 8 pad)
#define CSTR 65    // f32 elems per LDS C/T row (64 + 1 pad)

#define F_BYTES   134217728ull            // 2048 * 32 * 128 * 8 * 2B
#define WBF_ELEMS 131072                  // W1+W2 bf16

// f workspace layout (fragment-native):
//   ft[((b*32 + j) * 128 + row) * 8 + u],  j = col/8 (0..31), row 0..127
//   (row 0..63 = fq rows, 64..127 = fr rows), u = col%8.
// Consumer MFMA fragment (row r, cols lh*8+kc*16 .. +8) = one bf16x8 at
// j = 2*kc + lh -> consecutive lanes (l31) read consecutive 16B. Coalesced.

// ---------------------------------------------------------------------------
__global__ __launch_bounds__(256) void convert_w(const float* __restrict__ W1,
                                                 const float* __restrict__ W2,
                                                 bf16_t* __restrict__ wbf) {
    int i = blockIdx.x * 256 + threadIdx.x;   // grid 512
    if (i < 65536) wbf[i] = (bf16_t)W1[i];
    else           wbf[i] = (bf16_t)W2[i - 65536];
}

// ---------------------------------------------------------------------------
// Kernel A: 2-layer MLP, 64 rows per block. Single LDS activation buffer
// (36 KB) -> 4 blocks/CU. H lives in registers between layers.
// C/D layout of 32x32x16: n = lane&31, e = (reg&3)+8*(reg>>2)+4*lh.
// ---------------------------------------------------------------------------
__global__ __launch_bounds__(256, 4) void mlp_pair(
    const float* __restrict__ sq, const float* __restrict__ sr,
    const float* __restrict__ b1, const float* __restrict__ b2,
    const bf16_t* __restrict__ wbf, bf16_t* __restrict__ ft) {

    __shared__ bf16_t Xs[64 * XSTR];          // 33792 B
    __shared__ float  b1_s[256], b2_s[256];   //  2048 B

    const int bi = blockIdx.x;
    const int t  = threadIdx.x;
    const int ln = t & 63;
    const int wv = t >> 6;
    const int l31 = ln & 31;
    const int lh  = ln >> 5;
    const int b = bi >> 1, half = bi & 1;

    // ---- stage X (fp32 -> bf16) ----
    {
        const float4* s4 = (const float4*)((half ? sr : sq) + (size_t)b * 64 * 256);
        #pragma unroll
        for (int it = 0; it < 16; ++it) {
            const int i  = t + it * 256;
            const int r  = i >> 6;
            const int c4 = i & 63;
            float4 v = s4[i];
            bf16x4 p;
            p[0] = (bf16_t)v.x; p[1] = (bf16_t)v.y;
            p[2] = (bf16_t)v.z; p[3] = (bf16_t)v.w;
            *(bf16x4*)&Xs[(size_t)r * XSTR + c4 * 4] = p;
        }
        b1_s[t] = b1[t];
        b2_s[t] = b2[t];
    }
    __syncthreads();

    // ---- layer 1: H (this wave's 64 e-features for all 64 rows) -> regs ----
    bf16x4 hreg[2][2][4];   // [etp][z][g] : 32 VGPRs
    #pragma unroll
    for (int etp = 0; etp < 2; ++etp) {
        const int e0 = (wv * 2 + etp) * 32;
        const bf16_t* wrow = wbf + (size_t)(e0 + l31) * 256 + lh * 8;
        const bf16_t* x0 = Xs + (size_t)l31 * XSTR + lh * 8;
        const bf16_t* x1 = x0 + 32 * XSTR;
        f32x16 a[2];
        #pragma unroll
        for (int i = 0; i < 16; ++i) { a[0][i] = 0.0f; a[1][i] = 0.0f; }
        #pragma unroll
        for (int kg = 0; kg < 4; ++kg) {
            bf16x8 af[4];
            #pragma unroll
            for (int u = 0; u < 4; ++u) af[u] = *(const bf16x8*)(wrow + (kg * 4 + u) * 16);
            #pragma unroll
            for (int u = 0; u < 4; ++u) {
                const int kc = kg * 4 + u;
                bf16x8 bx0 = *(const bf16x8*)(x0 + kc * 16);
                bf16x8 bx1 = *(const bf16x8*)(x1 + kc * 16);
                a[0] = __builtin_amdgcn_mfma_f32_32x32x16_bf16(af[u], bx0, a[0], 0, 0, 0);
                a[1] = __builtin_amdgcn_mfma_f32_32x32x16_bf16(af[u], bx1, a[1], 0, 0, 0);
            }
        }
        #pragma unroll
        for (int z = 0; z < 2; ++z) {
            #pragma unroll
            for (int g = 0; g < 4; ++g) {
                const int e = e0 + 8 * g + 4 * lh;
                #pragma unroll
                for (int rr = 0; rr < 4; ++rr) {
                    float v = a[z][4 * g + rr] + b1_s[e + rr];
                    hreg[etp][z][g][rr] = (bf16_t)fmaxf(v, 0.0f);
                }
            }
        }
    }
    __syncthreads();             // all waves done READING Xs

    // ---- write H into Xs (overwrite) ----
    #pragma unroll
    for (int etp = 0; etp < 2; ++etp) {
        const int e0 = (wv * 2 + etp) * 32;
        #pragma unroll
        for (int z = 0; z < 2; ++z) {
            const int n = z * 32 + l31;
            #pragma unroll
            for (int g = 0; g < 4; ++g)
                *(bf16x4*)&Xs[(size_t)n * XSTR + e0 + 8 * g + 4 * lh] = hreg[etp][z][g];
        }
    }
    __syncthreads();

    // ---- layer 2: read H from Xs, store f directly to global (frag layout) ----
    const size_t ftb = (size_t)b * 32768;   // 32*128*8 elems per batch
    #pragma unroll
    for (int etp = 0; etp < 2; ++etp) {
        const int e0 = (wv * 2 + etp) * 32;
        const bf16_t* wrow = wbf + 65536 + (size_t)(e0 + l31) * 256 + lh * 8;
        const bf16_t* x0 = Xs + (size_t)l31 * XSTR + lh * 8;
        const bf16_t* x1 = x0 + 32 * XSTR;
        f32x16 a[2];
        #pragma unroll
        for (int i = 0; i < 16; ++i) { a[0][i] = 0.0f; a[1][i] = 0.0f; }
        #pragma unroll
        for (int kg = 0; kg < 4; ++kg) {
            bf16x8 af[4];
            #pragma unroll
            for (int u = 0; u < 4; ++u) af[u] = *(const bf16x8*)(wrow + (kg * 4 + u) * 16);
            #pragma unroll
            for (int u = 0; u < 4; ++u) {
                const int kc = kg * 4 + u;
                bf16x8 bx0 = *(const bf16x8*)(x0 + kc * 16);
                bf16x8 bx1 = *(const bf16x8*)(x1 + kc * 16);
                a[0] = __builtin_amdgcn_mfma_f32_32x32x16_bf16(af[u], bx0, a[0], 0, 0, 0);
                a[1] = __builtin_amdgcn_mfma_f32_32x32x16_bf16(af[u], bx1, a[1], 0, 0, 0);
            }
        }
        #pragma unroll
        for (int z = 0; z < 2; ++z) {
            const int row = half * 64 + z * 32 + l31;
            #pragma unroll
            for (int g = 0; g < 4; ++g) {
                const int e = e0 + 8 * g + 4 * lh;
                bf16x4 p;
                #pragma unroll
                for (int rr = 0; rr < 4; ++rr)
                    p[rr] = (bf16_t)(a[z][4 * g + rr] + b2_s[e + rr]);
                const int j = (wv * 2 + etp) * 4 + g;
                *(bf16x4*)&ft[ftb + ((size_t)j * 128 + row) * 8 + 4 * lh] = p;
            }
        }
    }
}

// ---------------------------------------------------------------------------
// Kernel B: per-batch cdist (fragments straight from global) + Sinkhorn +
// power iters. LDS ~35 KB -> 4 blocks/CU.
// ---------------------------------------------------------------------------
__global__ __launch_bounds__(256, 4) void sinkhorn_ot(
    const bf16_t* __restrict__ ft,
    const float* __restrict__ mq, const float* __restrict__ mr,
    float* __restrict__ out) {

    __shared__ float Cs[64 * CSTR];   // 16640 B
    __shared__ float Ts[64 * CSTR];   // 16640 B
    __shared__ float nrm[128];
    __shared__ float lmq_s[64], lmr_s[64], la_s[64], lb_s[64];
    __shared__ float red_s[4];

    const int b  = blockIdx.x;
    const int t  = threadIdx.x;
    const int ln = t & 63;
    const int wv = t >> 6;
    const int l31 = ln & 31;
    const int lh  = ln >> 5;
    const size_t ftb = (size_t)b * 32768;

    // ---- row norms ||f||^2 + small loads ----
    {
        const int r  = t >> 1;
        const int hf = t & 1;
        float s = 0.0f;
        #pragma unroll
        for (int j2 = 0; j2 < 16; ++j2) {
            const int j = hf * 16 + j2;
            bf16x8 v = *(const bf16x8*)&ft[ftb + ((size_t)j * 128 + r) * 8];
            #pragma unroll
            for (int u = 0; u < 8; ++u) { float f = (float)v[u]; s = fmaf(f, f, s); }
        }
        s += __shfl_xor(s, 1);
        if (hf == 0) nrm[r] = s;
        if (t < 64)        lmq_s[t]      = __logf(fmaxf(mq[(size_t)b * 64 + t], 1e-8f));
        else if (t < 128)  lmr_s[t - 64] = __logf(fmaxf(mr[(size_t)b * 64 + (t - 64)], 1e-8f));
        else if (t < 192)  lb_s[t - 128] = 0.0f;
    }
    __syncthreads();

    // ---- cdist via MFMA, fragments from global ----
    {
        const int qt = wv >> 1, rt = wv & 1;
        f32x16 acc;
        #pragma unroll
        for (int i = 0; i < 16; ++i) acc[i] = 0.0f;
        #pragma unroll
        for (int kc = 0; kc < 16; ++kc) {
            const size_t jb = ftb + (size_t)(2 * kc + lh) * 1024;   // j*128*8
            bf16x8 av = *(const bf16x8*)&ft[jb + (qt * 32 + l31) * 8];
            bf16x8 bv = *(const bf16x8*)&ft[jb + (64 + rt * 32 + l31) * 8];
            acc = __builtin_amdgcn_mfma_f32_32x32x16_bf16(av, bv, acc, 0, 0, 0);
        }
        const int m = rt * 32 + l31;
        const float nr_m = nrm[64 + m];
        float* outC = out + 2048 + (size_t)2048 * 4096 + (size_t)b * 4096;
        #pragma unroll
        for (int g = 0; g < 4; ++g) {
            #pragma unroll
            for (int rr = 0; rr < 4; ++rr) {
                const int q = qt * 32 + 8 * g + 4 * lh + rr;
                float d2 = nrm[q] + nr_m - 2.0f * acc[4 * g + rr];
                float cv = sqrtf(fmaxf(d2, 0.0f));
                Cs[q * CSTR + m] = cv;
                outC[q * 64 + m] = cv;
            }
        }
    }
    __syncthreads();

    // ---- Sinkhorn ----
    const int ki = t >> 2;
    const int jj = t & 3;
    float rowV[16], colV[16];
    #pragma unroll
    for (int i = 0; i < 16; ++i) {
        const int m2 = jj * 16 + i;
        rowV[i] = fmaf(Cs[ki * CSTR + m2], -IEPS, lmr_s[m2]);
        colV[i] = fmaf(Cs[m2 * CSTR + ki], -IEPS, lmq_s[m2]);
    }
    const float lmq_k = lmq_s[ki];
    const float lmr_m = lmr_s[ki];

    for (int it = 0; it < NITER; ++it) {
        float mx = -1e30f;
        #pragma unroll
        for (int i = 0; i < 16; ++i) mx = fmaxf(mx, rowV[i] + lb_s[jj * 16 + i]);
        mx = fmaxf(mx, __shfl_xor(mx, 1));
        mx = fmaxf(mx, __shfl_xor(mx, 2));
        float s = 0.0f;
        #pragma unroll
        for (int i = 0; i < 16; ++i) s += __expf(rowV[i] + lb_s[jj * 16 + i] - mx);
        s += __shfl_xor(s, 1);
        s += __shfl_xor(s, 2);
        if (jj == 0) la_s[ki] = -(lmq_k + mx + __logf(s));
        __syncthreads();

        mx = -1e30f;
        #pragma unroll
        for (int i = 0; i < 16; ++i) mx = fmaxf(mx, colV[i] + la_s[jj * 16 + i]);
        mx = fmaxf(mx, __shfl_xor(mx, 1));
        mx = fmaxf(mx, __shfl_xor(mx, 2));
        s = 0.0f;
        #pragma unroll
        for (int i = 0; i < 16; ++i) s += __expf(colV[i] + la_s[jj * 16 + i] - mx);
        s += __shfl_xor(s, 1);
        s += __shfl_xor(s, 2);
        if (jj == 0) lb_s[ki] = -(lmr_m + mx + __logf(s));
        __syncthreads();
    }

    // ---- T = exp(lK + la + lb) ----
    {
        const float base = lmq_k + la_s[ki];
        #pragma unroll
        for (int i = 0; i < 16; ++i) {
            const int m2 = jj * 16 + i;
            Ts[ki * CSTR + m2] = __expf(rowV[i] + lb_s[m2] + base);
        }
    }
    __syncthreads();

    // ---- power iterations ----
    for (int pi = 0; pi < MITER; ++pi) {
        float vv[16], rs = 0.0f;
        #pragma unroll
        for (int i = 0; i < 16; ++i) {
            float v = Ts[ki * CSTR + jj * 16 + i];
            v = v * v; vv[i] = v; rs += v;
        }
        rs += __shfl_xor(rs, 1); rs += __shfl_xor(rs, 2);
        float inv = 1.0f / (rs + 1e-8f);
        #pragma unroll
        for (int i = 0; i < 16; ++i) Ts[ki * CSTR + jj * 16 + i] = vv[i] * inv;
        __syncthreads();

        float cs = 0.0f;
        #pragma unroll
        for (int i = 0; i < 16; ++i) { float v = Ts[(jj * 16 + i) * CSTR + ki]; vv[i] = v; cs += v; }
        cs += __shfl_xor(cs, 1); cs += __shfl_xor(cs, 2);
        inv = 1.0f / (cs + 1e-8f);
        #pragma unroll
        for (int i = 0; i < 16; ++i) Ts[(jj * 16 + i) * CSTR + ki] = vv[i] * inv;
        __syncthreads();
    }

    // ---- write T, c = sum(T*C), sigmoid(-c) ----
    {
        float part = 0.0f;
        float tq[16];
        #pragma unroll
        for (int i = 0; i < 16; ++i) {
            const int m2 = jj * 16 + i;
            float tv = Ts[ki * CSTR + m2];
            tq[i] = tv;
            part = fmaf(tv, Cs[ki * CSTR + m2], part);
        }
        float* outT = out + 2048 + (size_t)b * 4096 + ki * 64 + jj * 16;
        #pragma unroll
        for (int q4 = 0; q4 < 4; ++q4) {
            ((float4*)outT)[q4] = make_float4(tq[4 * q4], tq[4 * q4 + 1],
                                              tq[4 * q4 + 2], tq[4 * q4 + 3]);
        }
        #pragma unroll
        for (int off = 1; off < 64; off <<= 1) part += __shfl_xor(part, off);
        if (ln == 0) red_s[wv] = part;
    }
    __syncthreads();
    if (t == 0) {
        float c = red_s[0] + red_s[1] + red_s[2] + red_s[3];
        out[2048 + (size_t)2 * 2048 * 4096 + b] = c;
        out[b] = 1.0f / (1.0f + __expf(c));
    }
}

// ===========================================================================
// Fallback (ws too small): round-1 fused kernel, proven correct.
// ===========================================================================
__device__ __forceinline__ void mlp_layer128(const bf16_t* __restrict__ in,
                                             const bf16_t* __restrict__ W,
                                             const float*  __restrict__ bias,
                                             bf16_t* __restrict__ outLds,
                                             bool relu, int ln, int wv) {
    const int l31 = ln & 31;
    const int lh  = ln >> 5;
    for (int etp = 0; etp < 2; ++etp) {
        const int e0 = (wv * 2 + etp) * 32;
        bf16x8 af[16];
        const bf16_t* wrow = W + (size_t)(e0 + l31) * 256 + lh * 8;
        #pragma unroll
        for (int kc = 0; kc < 16; ++kc) af[kc] = *(const bf16x8*)(wrow + kc * 16);
        #pragma unroll
        for (int ntp = 0; ntp < 2; ++ntp) {
            const bf16_t* x0 = in + (size_t)(ntp * 64 + l31) * XSTR + lh * 8;
            const bf16_t* x1 = x0 + 32 * XSTR;
            f32x16 a[2];
            #pragma unroll
            for (int i = 0; i < 16; ++i) { a[0][i] = 0.0f; a[1][i] = 0.0f; }
            #pragma unroll
            for (int kc = 0; kc < 16; ++kc) {
                bf16x8 bx0 = *(const bf16x8*)(x0 + kc * 16);
                bf16x8 bx1 = *(const bf16x8*)(x1 + kc * 16);
                a[0] = __builtin_amdgcn_mfma_f32_32x32x16_bf16(af[kc], bx0, a[0], 0, 0, 0);
                a[1] = __builtin_amdgcn_mfma_f32_32x32x16_bf16(af[kc], bx1, a[1], 0, 0, 0);
            }
            #pragma unroll
            for (int z = 0; z < 2; ++z) {
                const int n = ntp * 64 + z * 32 + l31;
                #pragma unroll
                for (int g = 0; g < 4; ++g) {
                    const int e = e0 + 8 * g + 4 * lh;
                    bf16x4 p;
                    #pragma unroll
                    for (int rr = 0; rr < 4; ++rr) {
                        float v = a[z][4 * g + rr] + bias[e + rr];
                        if (relu) v = fmaxf(v, 0.0f);
                        p[rr] = (bf16_t)v;
                    }
                    *(bf16x4*)&outLds[(size_t)n * XSTR + e] = p;
                }
            }
        }
    }
}

__global__ __launch_bounds__(256, 1) void sinkhorn_fused(
    const float* __restrict__ sq, const float* __restrict__ sr,
    const float* __restrict__ mq, const float* __restrict__ mr,
    const float* __restrict__ b1, const float* __restrict__ b2,
    const bf16_t* __restrict__ wbf,
    float* __restrict__ out) {

    __shared__ bf16_t Xs[128 * XSTR];
    __shared__ bf16_t Hs[128 * XSTR];
    __shared__ float  Cs[64 * CSTR];
    __shared__ float  nrm[128];
    __shared__ float  lmq_s[64], lmr_s[64], la_s[64], lb_s[64];
    __shared__ float  b1_s[256], b2_s[256];
    __shared__ float  red_s[4];

    const int b  = blockIdx.x;
    const int t  = threadIdx.x;
    const int ln = t & 63;
    const int wv = t >> 6;
    const int l31 = ln & 31;
    const int lh  = ln >> 5;

    {
        const float4* sq4 = (const float4*)(sq + (size_t)b * KK * DD);
        const float4* sr4 = (const float4*)(sr + (size_t)b * MM * DD);
        for (int i = t; i < 8192; i += 256) {
            const int r  = i >> 6;
            const int c4 = i & 63;
            float4 v = (r < 64) ? sq4[r * 64 + c4] : sr4[(r - 64) * 64 + c4];
            bf16x4 p;
            p[0] = (bf16_t)v.x; p[1] = (bf16_t)v.y;
            p[2] = (bf16_t)v.z; p[3] = (bf16_t)v.w;
            *(bf16x4*)&Xs[(size_t)r * XSTR + c4 * 4] = p;
        }
        b1_s[t] = b1[t];
        b2_s[t] = b2[t];
        if (t < 64)        lmq_s[t]       = __logf(fmaxf(mq[(size_t)b * 64 + t], 1e-8f));
        else if (t < 128)  lmr_s[t - 64]  = __logf(fmaxf(mr[(size_t)b * 64 + (t - 64)], 1e-8f));
        else if (t < 192)  lb_s[t - 128]  = 0.0f;
    }
    __syncthreads();
    mlp_layer128(Xs, wbf, b1_s, Hs, true, ln, wv);
    __syncthreads();
    mlp_layer128(Hs, wbf + 65536, b2_s, Xs, false, ln, wv);
    __syncthreads();
    {
        const int r  = t >> 1;
        const int hf = t & 1;
        const bf16_t* frow = &Xs[(size_t)r * XSTR + hf * 128];
        float s = 0.0f;
        #pragma unroll
        for (int c = 0; c < 16; ++c) {
            bf16x8 v = *(const bf16x8*)(frow + c * 8);
            #pragma unroll
            for (int j2 = 0; j2 < 8; ++j2) { float f = (float)v[j2]; s = fmaf(f, f, s); }
        }
        s += __shfl_xor(s, 1);
        if (hf == 0) nrm[r] = s;
    }
    __syncthreads();
    {
        const int qt = wv >> 1, rt = wv & 1;
        const bf16_t* qa = &Xs[(size_t)(qt * 32 + l31) * XSTR + lh * 8];
        const bf16_t* ra = &Xs[(size_t)(64 + rt * 32 + l31) * XSTR + lh * 8];
        f32x16 acc;
        #pragma unroll
        for (int i = 0; i < 16; ++i) acc[i] = 0.0f;
        #pragma unroll
        for (int kc = 0; kc < 16; ++kc) {
            bf16x8 av = *(const bf16x8*)(qa + kc * 16);
            bf16x8 bv = *(const bf16x8*)(ra + kc * 16);
            acc = __builtin_amdgcn_mfma_f32_32x32x16_bf16(av, bv, acc, 0, 0, 0);
        }
        float* outC = out + 2048 + (size_t)2048 * 4096 + (size_t)b * 4096;
        const int m = rt * 32 + l31;
        const float nr_m = nrm[64 + m];
        #pragma unroll
        for (int g = 0; g < 4; ++g) {
            #pragma unroll
            for (int rr = 0; rr < 4; ++rr) {
                const int q = qt * 32 + 8 * g + 4 * lh + rr;
                float d2 = nrm[q] + nr_m - 2.0f * acc[4 * g + rr];
                float cv = sqrtf(fmaxf(d2, 0.0f));
                Cs[q * CSTR + m] = cv;
                outC[q * 64 + m] = cv;
            }
        }
    }
    __syncthreads();

    const int ki = t >> 2;
    const int jj = t & 3;
    float rowV[16], colV[16];
    #pragma unroll
    for (int i = 0; i < 16; ++i) {
        const int m2 = jj * 16 + i;
        rowV[i] = fmaf(Cs[ki * CSTR + m2], -IEPS, lmr_s[m2]);
        colV[i] = fmaf(Cs[m2 * CSTR + ki], -IEPS, lmq_s[m2]);
    }
    const float lmq_k = lmq_s[ki];
    const float lmr_m = lmr_s[ki];

    for (int it = 0; it < NITER; ++it) {
        float mx = -1e30f;
        #pragma unroll
        for (int i = 0; i < 16; ++i) mx = fmaxf(mx, rowV[i] + lb_s[jj * 16 + i]);
        mx = fmaxf(mx, __shfl_xor(mx, 1));
        mx = fmaxf(mx, __shfl_xor(mx, 2));
        float s = 0.0f;
        #pragma unroll
        for (int i = 0; i < 16; ++i) s += __expf(rowV[i] + lb_s[jj * 16 + i] - mx);
        s += __shfl_xor(s, 1);
        s += __shfl_xor(s, 2);
        if (jj == 0) la_s[ki] = -(lmq_k + mx + __logf(s));
        __syncthreads();

        mx = -1e30f;
        #pragma unroll
        for (int i = 0; i < 16; ++i) mx = fmaxf(mx, colV[i] + la_s[jj * 16 + i]);
        mx = fmaxf(mx, __shfl_xor(mx, 1));
        mx = fmaxf(mx, __shfl_xor(mx, 2));
        s = 0.0f;
        #pragma unroll
        for (int i = 0; i < 16; ++i) s += __expf(colV[i] + la_s[jj * 16 + i] - mx);
        s += __shfl_xor(s, 1);
        s += __shfl_xor(s, 2);
        if (jj == 0) lb_s[ki] = -(lmr_m + mx + __logf(s));
        __syncthreads();
    }

    float* Ts = (float*)Hs;
    {
        const float base = lmq_k + la_s[ki];
        #pragma unroll
        for (int i = 0; i < 16; ++i) {
            const int m2 = jj * 16 + i;
            Ts[ki * CSTR + m2] = __expf(rowV[i] + lb_s[m2] + base);
        }
    }
    __syncthreads();

    for (int pi = 0; pi < MITER; ++pi) {
        float vv[16], rs = 0.0f;
        #pragma unroll
        for (int i = 0; i < 16; ++i) {
            float v = Ts[ki * CSTR + jj * 16 + i];
            v = v * v; vv[i] = v; rs += v;
        }
        rs += __shfl_xor(rs, 1); rs += __shfl_xor(rs, 2);
        float inv = 1.0f / (rs + 1e-8f);
        #pragma unroll
        for (int i = 0; i < 16; ++i) Ts[ki * CSTR + jj * 16 + i] = vv[i] * inv;
        __syncthreads();

        float cs = 0.0f;
        #pragma unroll
        for (int i = 0; i < 16; ++i) { float v = Ts[(jj * 16 + i) * CSTR + ki]; vv[i] = v; cs += v; }
        cs += __shfl_xor(cs, 1); cs += __shfl_xor(cs, 2);
        inv = 1.0f / (cs + 1e-8f);
        #pragma unroll
        for (int i = 0; i < 16; ++i) Ts[(jj * 16 + i) * CSTR + ki] = vv[i] * inv;
        __syncthreads();
    }

    {
        float part = 0.0f;
        float tq[16];
        #pragma unroll
        for (int i = 0; i < 16; ++i) {
            const int m2 = jj * 16 + i;
            float tv = Ts[ki * CSTR + m2];
            tq[i] = tv;
            part = fmaf(tv, Cs[ki * CSTR + m2], part);
        }
        float* outT = out + 2048 + (size_t)b * 4096 + ki * 64 + jj * 16;
        #pragma unroll
        for (int q4 = 0; q4 < 4; ++q4) {
            ((float4*)outT)[q4] = make_float4(tq[4 * q4], tq[4 * q4 + 1],
                                              tq[4 * q4 + 2], tq[4 * q4 + 3]);
        }
        #pragma unroll
        for (int off = 1; off < 64; off <<= 1) part += __shfl_xor(part, off);
        if (ln == 0) red_s[wv] = part;
    }
    __syncthreads();
    if (t == 0) {
        float c = red_s[0] + red_s[1] + red_s[2] + red_s[3];
        out[2048 + (size_t)2 * 2048 * 4096 + b] = c;
        out[b] = 1.0f / (1.0f + __expf(c));
    }
}

extern "C" void kernel_launch(void* const* d_in, const int* in_sizes, int n_in,
                              void* d_out, int out_size, void* d_ws, size_t ws_size,
                              hipStream_t stream) {
    const float* sq = (const float*)d_in[0];
    const float* sr = (const float*)d_in[1];
    const float* mq = (const float*)d_in[2];
    const float* mr = (const float*)d_in[3];
    const float* W1 = (const float*)d_in[4];
    const float* b1 = (const float*)d_in[5];
    const float* W2 = (const float*)d_in[6];
    const float* b2 = (const float*)d_in[7];

    const size_t need = F_BYTES + (size_t)WBF_ELEMS * 2;
    if (ws_size >= need) {
        bf16_t* fbuf = (bf16_t*)d_ws;
        bf16_t* wbf  = (bf16_t*)((char*)d_ws + F_BYTES);
        convert_w<<<512, 256, 0, stream>>>(W1, W2, wbf);
        mlp_pair<<<4096, 256, 0, stream>>>(sq, sr, b1, b2, wbf, fbuf);
        sinkhorn_ot<<<NB, 256, 0, stream>>>(fbuf, mq, mr, (float*)d_out);
    } else {
        bf16_t* wbf = (bf16_t*)d_ws;
        convert_w<<<512, 256, 0, stream>>>(W1, W2, wbf);
        sinkhorn_fused<<<NB, 256, 0, stream>>>(sq, sr, mq, mr, b1, b2, wbf, (float*)d_out);
    }
}

// Round 4
// 434.506 us; speedup vs baseline: 1.4467x; 1.1557x over previous
//
#include <hip/hip_runtime.h>
#include <math.h>

// Problem constants
#define NB    2048
#define KK    64
#define MM    64
#define DD    256
#define NITER 15
#define MITER 3
#define IEPS  20.0f   // 1/0.05

typedef __bf16 bf16_t;
typedef bf16_t bf16x8 __attribute__((ext_vector_type(8)));
typedef bf16_t bf16x4 __attribute__((ext_vector_type(4)));
typedef float  f32x16 __attribute__((ext_vector_type(16)));

#define XSTR 264   // bf16 elems per LDS activation row (256 + 8 pad)
#define CSTR 65    // f32 elems per LDS C/T row (64 + 1 pad)

#define F_BYTES   134217728ull            // 2048 * 32 * 128 * 8 * 2B
#define WBF_ELEMS 131072                  // W1+W2 bf16

// f workspace layout (fragment-native):
//   ft[((b*32 + j) * 128 + row) * 8 + u],  j = col/8 (0..31), row 0..127
//
// W workspace layout (fragment-native, NEW in R4):
//   wf[layer*65536 + ((eb*16 + kc)*64 + lane)*8 + u]
//   = W[eb*32 + (lane&31)][kc*16 + (lane>>5)*8 + u]
// A wave's MFMA A-fragment load = 64 lanes x 16 B contiguous (1 KB burst).

// ---------------------------------------------------------------------------
// Prep: convert W1,W2 fp32 row-major -> bf16 fragment-native layout.
// Destination-coalesced; scattered source reads (one-time, 131K elems).
// ---------------------------------------------------------------------------
__global__ __launch_bounds__(256) void convert_w_frag(const float* __restrict__ W1,
                                                      const float* __restrict__ W2,
                                                      bf16_t* __restrict__ wf) {
    const int j19 = blockIdx.x * 256 + threadIdx.x;   // grid 512 -> 131072
    const int layer = j19 >> 16;
    const int j = j19 & 65535;
    const int u    = j & 7;
    const int lane = (j >> 3) & 63;
    const int kc   = (j >> 9) & 15;
    const int eb   = j >> 13;
    const int l31  = lane & 31;
    const int lh   = lane >> 5;
    const int src  = (eb * 32 + l31) * 256 + kc * 16 + lh * 8 + u;
    wf[j19] = (bf16_t)(layer ? W2[src] : W1[src]);
}

// Row-major bf16 converter (fallback path only)
__global__ __launch_bounds__(256) void convert_w_row(const float* __restrict__ W1,
                                                     const float* __restrict__ W2,
                                                     bf16_t* __restrict__ wbf) {
    int i = blockIdx.x * 256 + threadIdx.x;
    if (i < 65536) wbf[i] = (bf16_t)W1[i];
    else           wbf[i] = (bf16_t)W2[i - 65536];
}

// ---------------------------------------------------------------------------
// Kernel A: 2-layer MLP, 64 rows per block, W loads via fragment-native
// layout (fully coalesced 1 KB bursts). LDS 36 KB -> 4 blocks/CU.
// C/D layout of 32x32x16: n = lane&31, e = (reg&3)+8*(reg>>2)+4*lh.
// ---------------------------------------------------------------------------
__global__ __launch_bounds__(256, 4) void mlp_pair(
    const float* __restrict__ sq, const float* __restrict__ sr,
    const float* __restrict__ b1, const float* __restrict__ b2,
    const bf16_t* __restrict__ wf, bf16_t* __restrict__ ft) {

    __shared__ bf16_t Xs[64 * XSTR];          // 33792 B
    __shared__ float  b1_s[256], b2_s[256];

    const int bi = blockIdx.x;
    const int t  = threadIdx.x;
    const int ln = t & 63;
    const int wv = t >> 6;
    const int l31 = ln & 31;
    const int lh  = ln >> 5;
    const int b = bi >> 1, half = bi & 1;

    // ---- stage X (fp32 -> bf16), coalesced global, conflict-free LDS ----
    {
        const float4* s4 = (const float4*)((half ? sr : sq) + (size_t)b * 64 * 256);
        #pragma unroll
        for (int it = 0; it < 16; ++it) {
            const int i  = t + it * 256;
            const int r  = i >> 6;      // wave-uniform row
            const int c4 = i & 63;
            float4 v = s4[i];
            bf16x4 p;
            p[0] = (bf16_t)v.x; p[1] = (bf16_t)v.y;
            p[2] = (bf16_t)v.z; p[3] = (bf16_t)v.w;
            *(bf16x4*)&Xs[(size_t)r * XSTR + c4 * 4] = p;
        }
        b1_s[t] = b1[t];
        b2_s[t] = b2[t];
    }
    __syncthreads();

    // ---- layer 1 -> hreg (this wave's 64 e-features for all 64 rows) ----
    bf16x4 hreg[2][2][4];   // [etp][z][g]
    #pragma unroll
    for (int etp = 0; etp < 2; ++etp) {
        const int eb = wv * 2 + etp;
        const bf16_t* wbase = wf + ((size_t)eb * 16) * 512 + ln * 8;
        const bf16_t* x0 = Xs + (size_t)l31 * XSTR + lh * 8;
        const bf16_t* x1 = x0 + 32 * XSTR;
        f32x16 a[2];
        #pragma unroll
        for (int i = 0; i < 16; ++i) { a[0][i] = 0.0f; a[1][i] = 0.0f; }
        #pragma unroll
        for (int kg = 0; kg < 2; ++kg) {
            bf16x8 af[8];
            #pragma unroll
            for (int u = 0; u < 8; ++u)
                af[u] = *(const bf16x8*)(wbase + (size_t)(kg * 8 + u) * 512);
            #pragma unroll
            for (int u = 0; u < 8; ++u) {
                const int kc = kg * 8 + u;
                bf16x8 bx0 = *(const bf16x8*)(x0 + kc * 16);
                bf16x8 bx1 = *(const bf16x8*)(x1 + kc * 16);
                a[0] = __builtin_amdgcn_mfma_f32_32x32x16_bf16(af[u], bx0, a[0], 0, 0, 0);
                a[1] = __builtin_amdgcn_mfma_f32_32x32x16_bf16(af[u], bx1, a[1], 0, 0, 0);
            }
        }
        const int e0 = eb * 32;
        #pragma unroll
        for (int z = 0; z < 2; ++z) {
            #pragma unroll
            for (int g = 0; g < 4; ++g) {
                const int e = e0 + 8 * g + 4 * lh;
                #pragma unroll
                for (int rr = 0; rr < 4; ++rr) {
                    float v = a[z][4 * g + rr] + b1_s[e + rr];
                    hreg[etp][z][g][rr] = (bf16_t)fmaxf(v, 0.0f);
                }
            }
        }
    }
    __syncthreads();             // all waves done READING Xs

    // ---- write H into Xs (overwrite) ----
    #pragma unroll
    for (int etp = 0; etp < 2; ++etp) {
        const int e0 = (wv * 2 + etp) * 32;
        #pragma unroll
        for (int z = 0; z < 2; ++z) {
            const int n = z * 32 + l31;
            #pragma unroll
            for (int g = 0; g < 4; ++g)
                *(bf16x4*)&Xs[(size_t)n * XSTR + e0 + 8 * g + 4 * lh] = hreg[etp][z][g];
        }
    }
    __syncthreads();

    // ---- layer 2: H from Xs, W2 frags coalesced, store f (frag layout) ----
    const size_t ftb = (size_t)b * 32768;
    #pragma unroll
    for (int etp = 0; etp < 2; ++etp) {
        const int eb = wv * 2 + etp;
        const bf16_t* wbase = wf + 65536 + ((size_t)eb * 16) * 512 + ln * 8;
        const bf16_t* x0 = Xs + (size_t)l31 * XSTR + lh * 8;
        const bf16_t* x1 = x0 + 32 * XSTR;
        f32x16 a[2];
        #pragma unroll
        for (int i = 0; i < 16; ++i) { a[0][i] = 0.0f; a[1][i] = 0.0f; }
        #pragma unroll
        for (int kg = 0; kg < 2; ++kg) {
            bf16x8 af[8];
            #pragma unroll
            for (int u = 0; u < 8; ++u)
                af[u] = *(const bf16x8*)(wbase + (size_t)(kg * 8 + u) * 512);
            #pragma unroll
            for (int u = 0; u < 8; ++u) {
                const int kc = kg * 8 + u;
                bf16x8 bx0 = *(const bf16x8*)(x0 + kc * 16);
                bf16x8 bx1 = *(const bf16x8*)(x1 + kc * 16);
                a[0] = __builtin_amdgcn_mfma_f32_32x32x16_bf16(af[u], bx0, a[0], 0, 0, 0);
                a[1] = __builtin_amdgcn_mfma_f32_32x32x16_bf16(af[u], bx1, a[1], 0, 0, 0);
            }
        }
        const int e0 = eb * 32;
        #pragma unroll
        for (int z = 0; z < 2; ++z) {
            const int row = half * 64 + z * 32 + l31;
            #pragma unroll
            for (int g = 0; g < 4; ++g) {
                const int e = e0 + 8 * g + 4 * lh;
                bf16x4 p;
                #pragma unroll
                for (int rr = 0; rr < 4; ++rr)
                    p[rr] = (bf16_t)(a[z][4 * g + rr] + b2_s[e + rr]);
                const int j = eb * 4 + g;
                *(bf16x4*)&ft[ftb + ((size_t)j * 128 + row) * 8 + 4 * lh] = p;
            }
        }
    }
}

// ---------------------------------------------------------------------------
// Kernel B: per-batch cdist (fragments straight from global) + Sinkhorn +
// power iters. LDS ~35 KB -> 4 blocks/CU.  (unchanged from R3)
// ---------------------------------------------------------------------------
__global__ __launch_bounds__(256, 4) void sinkhorn_ot(
    const bf16_t* __restrict__ ft,
    const float* __restrict__ mq, const float* __restrict__ mr,
    float* __restrict__ out) {

    __shared__ float Cs[64 * CSTR];   // 16640 B
    __shared__ float Ts[64 * CSTR];   // 16640 B
    __shared__ float nrm[128];
    __shared__ float lmq_s[64], lmr_s[64], la_s[64], lb_s[64];
    __shared__ float red_s[4];

    const int b  = blockIdx.x;
    const int t  = threadIdx.x;
    const int ln = t & 63;
    const int wv = t >> 6;
    const int l31 = ln & 31;
    const int lh  = ln >> 5;
    const size_t ftb = (size_t)b * 32768;

    // ---- row norms ||f||^2 + small loads ----
    {
        const int r  = t >> 1;
        const int hf = t & 1;
        float s = 0.0f;
        #pragma unroll
        for (int j2 = 0; j2 < 16; ++j2) {
            const int j = hf * 16 + j2;
            bf16x8 v = *(const bf16x8*)&ft[ftb + ((size_t)j * 128 + r) * 8];
            #pragma unroll
            for (int u = 0; u < 8; ++u) { float f = (float)v[u]; s = fmaf(f, f, s); }
        }
        s += __shfl_xor(s, 1);
        if (hf == 0) nrm[r] = s;
        if (t < 64)        lmq_s[t]      = __logf(fmaxf(mq[(size_t)b * 64 + t], 1e-8f));
        else if (t < 128)  lmr_s[t - 64] = __logf(fmaxf(mr[(size_t)b * 64 + (t - 64)], 1e-8f));
        else if (t < 192)  lb_s[t - 128] = 0.0f;
    }
    __syncthreads();

    // ---- cdist via MFMA, fragments from global ----
    {
        const int qt = wv >> 1, rt = wv & 1;
        f32x16 acc;
        #pragma unroll
        for (int i = 0; i < 16; ++i) acc[i] = 0.0f;
        #pragma unroll
        for (int kc = 0; kc < 16; ++kc) {
            const size_t jb = ftb + (size_t)(2 * kc + lh) * 1024;   // j*128*8
            bf16x8 av = *(const bf16x8*)&ft[jb + (qt * 32 + l31) * 8];
            bf16x8 bv = *(const bf16x8*)&ft[jb + (64 + rt * 32 + l31) * 8];
            acc = __builtin_amdgcn_mfma_f32_32x32x16_bf16(av, bv, acc, 0, 0, 0);
        }
        const int m = rt * 32 + l31;
        const float nr_m = nrm[64 + m];
        float* outC = out + 2048 + (size_t)2048 * 4096 + (size_t)b * 4096;
        #pragma unroll
        for (int g = 0; g < 4; ++g) {
            #pragma unroll
            for (int rr = 0; rr < 4; ++rr) {
                const int q = qt * 32 + 8 * g + 4 * lh + rr;
                float d2 = nrm[q] + nr_m - 2.0f * acc[4 * g + rr];
                float cv = sqrtf(fmaxf(d2, 0.0f));
                Cs[q * CSTR + m] = cv;
                outC[q * 64 + m] = cv;
            }
        }
    }
    __syncthreads();

    // ---- Sinkhorn ----
    const int ki = t >> 2;
    const int jj = t & 3;
    float rowV[16], colV[16];
    #pragma unroll
    for (int i = 0; i < 16; ++i) {
        const int m2 = jj * 16 + i;
        rowV[i] = fmaf(Cs[ki * CSTR + m2], -IEPS, lmr_s[m2]);
        colV[i] = fmaf(Cs[m2 * CSTR + ki], -IEPS, lmq_s[m2]);
    }
    const float lmq_k = lmq_s[ki];
    const float lmr_m = lmr_s[ki];

    for (int it = 0; it < NITER; ++it) {
        float mx = -1e30f;
        #pragma unroll
        for (int i = 0; i < 16; ++i) mx = fmaxf(mx, rowV[i] + lb_s[jj * 16 + i]);
        mx = fmaxf(mx, __shfl_xor(mx, 1));
        mx = fmaxf(mx, __shfl_xor(mx, 2));
        float s = 0.0f;
        #pragma unroll
        for (int i = 0; i < 16; ++i) s += __expf(rowV[i] + lb_s[jj * 16 + i] - mx);
        s += __shfl_xor(s, 1);
        s += __shfl_xor(s, 2);
        if (jj == 0) la_s[ki] = -(lmq_k + mx + __logf(s));
        __syncthreads();

        mx = -1e30f;
        #pragma unroll
        for (int i = 0; i < 16; ++i) mx = fmaxf(mx, colV[i] + la_s[jj * 16 + i]);
        mx = fmaxf(mx, __shfl_xor(mx, 1));
        mx = fmaxf(mx, __shfl_xor(mx, 2));
        float s2 = 0.0f;
        #pragma unroll
        for (int i = 0; i < 16; ++i) s2 += __expf(colV[i] + la_s[jj * 16 + i] - mx);
        s2 += __shfl_xor(s2, 1);
        s2 += __shfl_xor(s2, 2);
        if (jj == 0) lb_s[ki] = -(lmr_m + mx + __logf(s2));
        __syncthreads();
    }

    // ---- T = exp(lK + la + lb) ----
    {
        const float base = lmq_k + la_s[ki];
        #pragma unroll
        for (int i = 0; i < 16; ++i) {
            const int m2 = jj * 16 + i;
            Ts[ki * CSTR + m2] = __expf(rowV[i] + lb_s[m2] + base);
        }
    }
    __syncthreads();

    // ---- power iterations ----
    for (int pi = 0; pi < MITER; ++pi) {
        float vv[16], rs = 0.0f;
        #pragma unroll
        for (int i = 0; i < 16; ++i) {
            float v = Ts[ki * CSTR + jj * 16 + i];
            v = v * v; vv[i] = v; rs += v;
        }
        rs += __shfl_xor(rs, 1); rs += __shfl_xor(rs, 2);
        float inv = 1.0f / (rs + 1e-8f);
        #pragma unroll
        for (int i = 0; i < 16; ++i) Ts[ki * CSTR + jj * 16 + i] = vv[i] * inv;
        __syncthreads();

        float cs = 0.0f;
        #pragma unroll
        for (int i = 0; i < 16; ++i) { float v = Ts[(jj * 16 + i) * CSTR + ki]; vv[i] = v; cs += v; }
        cs += __shfl_xor(cs, 1); cs += __shfl_xor(cs, 2);
        inv = 1.0f / (cs + 1e-8f);
        #pragma unroll
        for (int i = 0; i < 16; ++i) Ts[(jj * 16 + i) * CSTR + ki] = vv[i] * inv;
        __syncthreads();
    }

    // ---- write T, c = sum(T*C), sigmoid(-c) ----
    {
        float part = 0.0f;
        float tq[16];
        #pragma unroll
        for (int i = 0; i < 16; ++i) {
            const int m2 = jj * 16 + i;
            float tv = Ts[ki * CSTR + m2];
            tq[i] = tv;
            part = fmaf(tv, Cs[ki * CSTR + m2], part);
        }
        float* outT = out + 2048 + (size_t)b * 4096 + ki * 64 + jj * 16;
        #pragma unroll
        for (int q4 = 0; q4 < 4; ++q4) {
            ((float4*)outT)[q4] = make_float4(tq[4 * q4], tq[4 * q4 + 1],
                                              tq[4 * q4 + 2], tq[4 * q4 + 3]);
        }
        #pragma unroll
        for (int off = 1; off < 64; off <<= 1) part += __shfl_xor(part, off);
        if (ln == 0) red_s[wv] = part;
    }
    __syncthreads();
    if (t == 0) {
        float c = red_s[0] + red_s[1] + red_s[2] + red_s[3];
        out[2048 + (size_t)2 * 2048 * 4096 + b] = c;
        out[b] = 1.0f / (1.0f + __expf(c));
    }
}

// ===========================================================================
// Fallback (ws too small): round-1 fused kernel, proven correct.
// Uses ROW-MAJOR wbf (convert_w_row).
// ===========================================================================
__device__ __forceinline__ void mlp_layer128(const bf16_t* __restrict__ in,
                                             const bf16_t* __restrict__ W,
                                             const float*  __restrict__ bias,
                                             bf16_t* __restrict__ outLds,
                                             bool relu, int ln, int wv) {
    const int l31 = ln & 31;
    const int lh  = ln >> 5;
    for (int etp = 0; etp < 2; ++etp) {
        const int e0 = (wv * 2 + etp) * 32;
        bf16x8 af[16];
        const bf16_t* wrow = W + (size_t)(e0 + l31) * 256 + lh * 8;
        #pragma unroll
        for (int kc = 0; kc < 16; ++kc) af[kc] = *(const bf16x8*)(wrow + kc * 16);
        #pragma unroll
        for (int ntp = 0; ntp < 2; ++ntp) {
            const bf16_t* x0 = in + (size_t)(ntp * 64 + l31) * XSTR + lh * 8;
            const bf16_t* x1 = x0 + 32 * XSTR;
            f32x16 a[2];
            #pragma unroll
            for (int i = 0; i < 16; ++i) { a[0][i] = 0.0f; a[1][i] = 0.0f; }
            #pragma unroll
            for (int kc = 0; kc < 16; ++kc) {
                bf16x8 bx0 = *(const bf16x8*)(x0 + kc * 16);
                bf16x8 bx1 = *(const bf16x8*)(x1 + kc * 16);
                a[0] = __builtin_amdgcn_mfma_f32_32x32x16_bf16(af[kc], bx0, a[0], 0, 0, 0);
                a[1] = __builtin_amdgcn_mfma_f32_32x32x16_bf16(af[kc], bx1, a[1], 0, 0, 0);
            }
            #pragma unroll
            for (int z = 0; z < 2; ++z) {
                const int n = ntp * 64 + z * 32 + l31;
                #pragma unroll
                for (int g = 0; g < 4; ++g) {
                    const int e = e0 + 8 * g + 4 * lh;
                    bf16x4 p;
                    #pragma unroll
                    for (int rr = 0; rr < 4; ++rr) {
                        float v = a[z][4 * g + rr] + bias[e + rr];
                        if (relu) v = fmaxf(v, 0.0f);
                        p[rr] = (bf16_t)v;
                    }
                    *(bf16x4*)&outLds[(size_t)n * XSTR + e] = p;
                }
            }
        }
    }
}

__global__ __launch_bounds__(256, 1) void sinkhorn_fused(
    const float* __restrict__ sq, const float* __restrict__ sr,
    const float* __restrict__ mq, const float* __restrict__ mr,
    const float* __restrict__ b1, const float* __restrict__ b2,
    const bf16_t* __restrict__ wbf,
    float* __restrict__ out) {

    __shared__ bf16_t Xs[128 * XSTR];
    __shared__ bf16_t Hs[128 * XSTR];
    __shared__ float  Cs[64 * CSTR];
    __shared__ float  nrm[128];
    __shared__ float  lmq_s[64], lmr_s[64], la_s[64], lb_s[64];
    __shared__ float  b1_s[256], b2_s[256];
    __shared__ float  red_s[4];

    const int b  = blockIdx.x;
    const int t  = threadIdx.x;
    const int ln = t & 63;
    const int wv = t >> 6;
    const int l31 = ln & 31;
    const int lh  = ln >> 5;

    {
        const float4* sq4 = (const float4*)(sq + (size_t)b * KK * DD);
        const float4* sr4 = (const float4*)(sr + (size_t)b * MM * DD);
        for (int i = t; i < 8192; i += 256) {
            const int r  = i >> 6;
            const int c4 = i & 63;
            float4 v = (r < 64) ? sq4[r * 64 + c4] : sr4[(r - 64) * 64 + c4];
            bf16x4 p;
            p[0] = (bf16_t)v.x; p[1] = (bf16_t)v.y;
            p[2] = (bf16_t)v.z; p[3] = (bf16_t)v.w;
            *(bf16x4*)&Xs[(size_t)r * XSTR + c4 * 4] = p;
        }
        b1_s[t] = b1[t];
        b2_s[t] = b2[t];
        if (t < 64)        lmq_s[t]       = __logf(fmaxf(mq[(size_t)b * 64 + t], 1e-8f));
        else if (t < 128)  lmr_s[t - 64]  = __logf(fmaxf(mr[(size_t)b * 64 + (t - 64)], 1e-8f));
        else if (t < 192)  lb_s[t - 128]  = 0.0f;
    }
    __syncthreads();
    mlp_layer128(Xs, wbf, b1_s, Hs, true, ln, wv);
    __syncthreads();
    mlp_layer128(Hs, wbf + 65536, b2_s, Xs, false, ln, wv);
    __syncthreads();
    {
        const int r  = t >> 1;
        const int hf = t & 1;
        const bf16_t* frow = &Xs[(size_t)r * XSTR + hf * 128];
        float s = 0.0f;
        #pragma unroll
        for (int c = 0; c < 16; ++c) {
            bf16x8 v = *(const bf16x8*)(frow + c * 8);
            #pragma unroll
            for (int j2 = 0; j2 < 8; ++j2) { float f = (float)v[j2]; s = fmaf(f, f, s); }
        }
        s += __shfl_xor(s, 1);
        if (hf == 0) nrm[r] = s;
    }
    __syncthreads();
    {
        const int qt = wv >> 1, rt = wv & 1;
        const bf16_t* qa = &Xs[(size_t)(qt * 32 + l31) * XSTR + lh * 8];
        const bf16_t* ra = &Xs[(size_t)(64 + rt * 32 + l31) * XSTR + lh * 8];
        f32x16 acc;
        #pragma unroll
        for (int i = 0; i < 16; ++i) acc[i] = 0.0f;
        #pragma unroll
        for (int kc = 0; kc < 16; ++kc) {
            bf16x8 av = *(const bf16x8*)(qa + kc * 16);
            bf16x8 bv = *(const bf16x8*)(ra + kc * 16);
            acc = __builtin_amdgcn_mfma_f32_32x32x16_bf16(av, bv, acc, 0, 0, 0);
        }
        float* outC = out + 2048 + (size_t)2048 * 4096 + (size_t)b * 4096;
        const int m = rt * 32 + l31;
        const float nr_m = nrm[64 + m];
        #pragma unroll
        for (int g = 0; g < 4; ++g) {
            #pragma unroll
            for (int rr = 0; rr < 4; ++rr) {
                const int q = qt * 32 + 8 * g + 4 * lh + rr;
                float d2 = nrm[q] + nr_m - 2.0f * acc[4 * g + rr];
                float cv = sqrtf(fmaxf(d2, 0.0f));
                Cs[q * CSTR + m] = cv;
                outC[q * 64 + m] = cv;
            }
        }
    }
    __syncthreads();

    const int ki = t >> 2;
    const int jj = t & 3;
    float rowV[16], colV[16];
    #pragma unroll
    for (int i = 0; i < 16; ++i) {
        const int m2 = jj * 16 + i;
        rowV[i] = fmaf(Cs[ki * CSTR + m2], -IEPS, lmr_s[m2]);
        colV[i] = fmaf(Cs[m2 * CSTR + ki], -IEPS, lmq_s[m2]);
    }
    const float lmq_k = lmq_s[ki];
    const float lmr_m = lmr_s[ki];

    for (int it = 0; it < NITER; ++it) {
        float mx = -1e30f;
        #pragma unroll
        for (int i = 0; i < 16; ++i) mx = fmaxf(mx, rowV[i] + lb_s[jj * 16 + i]);
        mx = fmaxf(mx, __shfl_xor(mx, 1));
        mx = fmaxf(mx, __shfl_xor(mx, 2));
        float s = 0.0f;
        #pragma unroll
        for (int i = 0; i < 16; ++i) s += __expf(rowV[i] + lb_s[jj * 16 + i] - mx);
        s += __shfl_xor(s, 1);
        s += __shfl_xor(s, 2);
        if (jj == 0) la_s[ki] = -(lmq_k + mx + __logf(s));
        __syncthreads();

        mx = -1e30f;
        #pragma unroll
        for (int i = 0; i < 16; ++i) mx = fmaxf(mx, colV[i] + la_s[jj * 16 + i]);
        mx = fmaxf(mx, __shfl_xor(mx, 1));
        mx = fmaxf(mx, __shfl_xor(mx, 2));
        float s2 = 0.0f;
        #pragma unroll
        for (int i = 0; i < 16; ++i) s2 += __expf(colV[i] + la_s[jj * 16 + i] - mx);
        s2 += __shfl_xor(s2, 1);
        s2 += __shfl_xor(s2, 2);
        if (jj == 0) lb_s[ki] = -(lmr_m + mx + __logf(s2));
        __syncthreads();
    }

    float* Ts = (float*)Hs;
    {
        const float base = lmq_k + la_s[ki];
        #pragma unroll
        for (int i = 0; i < 16; ++i) {
            const int m2 = jj * 16 + i;
            Ts[ki * CSTR + m2] = __expf(rowV[i] + lb_s[m2] + base);
        }
    }
    __syncthreads();

    for (int pi = 0; pi < MITER; ++pi) {
        float vv[16], rs = 0.0f;
        #pragma unroll
        for (int i = 0; i < 16; ++i) {
            float v = Ts[ki * CSTR + jj * 16 + i];
            v = v * v; vv[i] = v; rs += v;
        }
        rs += __shfl_xor(rs, 1); rs += __shfl_xor(rs, 2);
        float inv = 1.0f / (rs + 1e-8f);
        #pragma unroll
        for (int i = 0; i < 16; ++i) Ts[ki * CSTR + jj * 16 + i] = vv[i] * inv;
        __syncthreads();

        float cs = 0.0f;
        #pragma unroll
        for (int i = 0; i < 16; ++i) { float v = Ts[(jj * 16 + i) * CSTR + ki]; vv[i] = v; cs += v; }
        cs += __shfl_xor(cs, 1); cs += __shfl_xor(cs, 2);
        inv = 1.0f / (cs + 1e-8f);
        #pragma unroll
        for (int i = 0; i < 16; ++i) Ts[(jj * 16 + i) * CSTR + ki] = vv[i] * inv;
        __syncthreads();
    }

    {
        float part = 0.0f;
        float tq[16];
        #pragma unroll
        for (int i = 0; i < 16; ++i) {
            const int m2 = jj * 16 + i;
            float tv = Ts[ki * CSTR + m2];
            tq[i] = tv;
            part = fmaf(tv, Cs[ki * CSTR + m2], part);
        }
        float* outT = out + 2048 + (size_t)b * 4096 + ki * 64 + jj * 16;
        #pragma unroll
        for (int q4 = 0; q4 < 4; ++q4) {
            ((float4*)outT)[q4] = make_float4(tq[4 * q4], tq[4 * q4 + 1],
                                              tq[4 * q4 + 2], tq[4 * q4 + 3]);
        }
        #pragma unroll
        for (int off = 1; off < 64; off <<= 1) part += __shfl_xor(part, off);
        if (ln == 0) red_s[wv] = part;
    }
    __syncthreads();
    if (t == 0) {
        float c = red_s[0] + red_s[1] + red_s[2] + red_s[3];
        out[2048 + (size_t)2 * 2048 * 4096 + b] = c;
        out[b] = 1.0f / (1.0f + __expf(c));
    }
}

extern "C" void kernel_launch(void* const* d_in, const int* in_sizes, int n_in,
                              void* d_out, int out_size, void* d_ws, size_t ws_size,
                              hipStream_t stream) {
    const float* sq = (const float*)d_in[0];
    const float* sr = (const float*)d_in[1];
    const float* mq = (const float*)d_in[2];
    const float* mr = (const float*)d_in[3];
    const float* W1 = (const float*)d_in[4];
    const float* b1 = (const float*)d_in[5];
    const float* W2 = (const float*)d_in[6];
    const float* b2 = (const float*)d_in[7];

    const size_t need = F_BYTES + (size_t)WBF_ELEMS * 2;
    if (ws_size >= need) {
        bf16_t* fbuf = (bf16_t*)d_ws;
        bf16_t* wf   = (bf16_t*)((char*)d_ws + F_BYTES);
        convert_w_frag<<<512, 256, 0, stream>>>(W1, W2, wf);
        mlp_pair<<<4096, 256, 0, stream>>>(sq, sr, b1, b2, wf, fbuf);
        sinkhorn_ot<<<NB, 256, 0, stream>>>(fbuf, mq, mr, (float*)d_out);
    } else {
        bf16_t* wbf = (bf16_t*)d_ws;
        convert_w_row<<<512, 256, 0, stream>>>(W1, W2, wbf);
        sinkhorn_fused<<<NB, 256, 0, stream>>>(sq, sr, mq, mr, b1, b2, wbf, (float*)d_out);
    }
}

// Round 5
// 432.400 us; speedup vs baseline: 1.4538x; 1.0049x over previous
//
#include <hip/hip_runtime.h>
#include <math.h>

// Problem constants
#define NB    2048
#define KK    64
#define MM    64
#define DD    256
#define NITER 15
#define MITER 3
#define IEPS  20.0f   // 1/0.05

typedef __bf16 bf16_t;
typedef bf16_t bf16x8 __attribute__((ext_vector_type(8)));
typedef bf16_t bf16x4 __attribute__((ext_vector_type(4)));
typedef float  f32x16 __attribute__((ext_vector_type(16)));

#define XSTR 264   // bf16 elems per LDS activation row (256 + 8 pad)
#define CSTR 65    // f32 elems per LDS C/T row (64 + 1 pad)

// W workspace layout (fragment-native):
//   wf[layer*65536 + ((eb*16 + kc)*64 + lane)*8 + u]
//   = W[eb*32 + (lane&31)][kc*16 + (lane>>5)*8 + u]
// A wave's MFMA A-fragment load = 64 lanes x 16 B contiguous (1 KB burst).

__global__ __launch_bounds__(256) void convert_w_frag(const float* __restrict__ W1,
                                                      const float* __restrict__ W2,
                                                      bf16_t* __restrict__ wf) {
    const int j19 = blockIdx.x * 256 + threadIdx.x;   // grid 512 -> 131072
    const int layer = j19 >> 16;
    const int j = j19 & 65535;
    const int u    = j & 7;
    const int lane = (j >> 3) & 63;
    const int kc   = (j >> 9) & 15;
    const int eb   = j >> 13;
    const int l31  = lane & 31;
    const int lh   = lane >> 5;
    const int src  = (eb * 32 + l31) * 256 + kc * 16 + lh * 8 + u;
    wf[j19] = (bf16_t)(layer ? W2[src] : W1[src]);
}

// ---------------------------------------------------------------------------
// Fully fused kernel: one batch per block, 512 threads (8 waves).
// Wave wv owns feature slice e in [wv*32, wv*32+32) for both MLP layers.
// LDS Xs region is reused: X -> H -> f -> {Cs, Ts}.
// ---------------------------------------------------------------------------
__global__ __launch_bounds__(512, 4) void sinkhorn_all(
    const float* __restrict__ sq, const float* __restrict__ sr,
    const float* __restrict__ mq, const float* __restrict__ mr,
    const float* __restrict__ b1, const float* __restrict__ b2,
    const bf16_t* __restrict__ wf,
    float* __restrict__ out) {

    __shared__ __align__(16) char smem[128 * XSTR * 2];   // 67584 B
    bf16_t* Xs = (bf16_t*)smem;
    float*  Cs = (float*)smem;                      // overlay after f is dead
    float*  Ts = (float*)(smem + 64 * CSTR * 4);
    __shared__ float nrm[128];
    __shared__ float lmq_s[64], lmr_s[64], la_s[64], lb_s[64];
    __shared__ float b1_s[256], b2_s[256];
    __shared__ float red_s[8];

    const int b  = blockIdx.x;
    const int t  = threadIdx.x;
    const int ln = t & 63;
    const int wv = t >> 6;          // 0..7
    const int l31 = ln & 31;
    const int lh  = ln >> 5;

    // ---- Phase 0: stage X = [sq_b ; sr_b] fp32 -> bf16, max load ILP ----
    {
        const float4* sq4 = (const float4*)(sq + (size_t)b * 64 * 256);
        const float4* sr4 = (const float4*)(sr + (size_t)b * 64 * 256);
        float4 xr[16];
        #pragma unroll
        for (int it = 0; it < 16; ++it) {
            const int r = wv + it * 8;          // wave-uniform row 0..127
            xr[it] = (r < 64) ? sq4[r * 64 + ln] : sr4[(r - 64) * 64 + ln];
        }
        #pragma unroll
        for (int it = 0; it < 16; ++it) {
            const int r = wv + it * 8;
            bf16x4 p;
            p[0] = (bf16_t)xr[it].x; p[1] = (bf16_t)xr[it].y;
            p[2] = (bf16_t)xr[it].z; p[3] = (bf16_t)xr[it].w;
            *(bf16x4*)&Xs[(size_t)r * XSTR + ln * 4] = p;
        }
        if (t < 256) b1_s[t] = b1[t];
        else         b2_s[t - 256] = b2[t - 256];
        if (t >= 256) {
            const int u = t - 256;               // 0..255
            if (u < 64)        lmq_s[u]       = __logf(fmaxf(mq[(size_t)b * 64 + u], 1e-8f));
            else if (u < 128)  lmr_s[u - 64]  = __logf(fmaxf(mr[(size_t)b * 64 + (u - 64)], 1e-8f));
            else if (u < 192)  lb_s[u - 128]  = 0.0f;
        }
    }
    __syncthreads();

    // ---- Phase 1: layer 1, H -> hreg ----
    bf16x4 hreg[2][2][4];   // [half][z][g]
    {
        const bf16_t* wbase = wf + ((size_t)wv * 16) * 512 + ln * 8;
        f32x16 acc[2][2];
        #pragma unroll
        for (int i = 0; i < 16; ++i) {
            acc[0][0][i] = 0.0f; acc[0][1][i] = 0.0f;
            acc[1][0][i] = 0.0f; acc[1][1][i] = 0.0f;
        }
        #pragma unroll
        for (int kg = 0; kg < 2; ++kg) {
            bf16x8 af[8];
            #pragma unroll
            for (int u = 0; u < 8; ++u)
                af[u] = *(const bf16x8*)(wbase + (size_t)(kg * 8 + u) * 512);
            #pragma unroll
            for (int half = 0; half < 2; ++half) {
                const bf16_t* x0 = Xs + (size_t)(half * 64 + l31) * XSTR + lh * 8;
                const bf16_t* x1 = x0 + 32 * XSTR;
                #pragma unroll
                for (int u = 0; u < 8; ++u) {
                    const int kc = kg * 8 + u;
                    bf16x8 bx0 = *(const bf16x8*)(x0 + kc * 16);
                    bf16x8 bx1 = *(const bf16x8*)(x1 + kc * 16);
                    acc[half][0] = __builtin_amdgcn_mfma_f32_32x32x16_bf16(af[u], bx0, acc[half][0], 0, 0, 0);
                    acc[half][1] = __builtin_amdgcn_mfma_f32_32x32x16_bf16(af[u], bx1, acc[half][1], 0, 0, 0);
                }
            }
        }
        const int e0 = wv * 32;
        #pragma unroll
        for (int half = 0; half < 2; ++half)
            #pragma unroll
            for (int z = 0; z < 2; ++z)
                #pragma unroll
                for (int g = 0; g < 4; ++g) {
                    const int e = e0 + 8 * g + 4 * lh;
                    #pragma unroll
                    for (int rr = 0; rr < 4; ++rr) {
                        float v = acc[half][z][4 * g + rr] + b1_s[e + rr];
                        hreg[half][z][g][rr] = (bf16_t)fmaxf(v, 0.0f);
                    }
                }
    }
    __syncthreads();             // all waves done reading X

    // ---- write H over Xs ----
    {
        const int e0 = wv * 32;
        #pragma unroll
        for (int half = 0; half < 2; ++half)
            #pragma unroll
            for (int z = 0; z < 2; ++z) {
                const int n = half * 64 + z * 32 + l31;
                #pragma unroll
                for (int g = 0; g < 4; ++g)
                    *(bf16x4*)&Xs[(size_t)n * XSTR + e0 + 8 * g + 4 * lh] = hreg[half][z][g];
            }
    }
    __syncthreads();

    // ---- Phase 2: layer 2, f -> hreg, then overwrite Xs ----
    {
        const bf16_t* wbase = wf + 65536 + ((size_t)wv * 16) * 512 + ln * 8;
        f32x16 acc[2][2];
        #pragma unroll
        for (int i = 0; i < 16; ++i) {
            acc[0][0][i] = 0.0f; acc[0][1][i] = 0.0f;
            acc[1][0][i] = 0.0f; acc[1][1][i] = 0.0f;
        }
        #pragma unroll
        for (int kg = 0; kg < 2; ++kg) {
            bf16x8 af[8];
            #pragma unroll
            for (int u = 0; u < 8; ++u)
                af[u] = *(const bf16x8*)(wbase + (size_t)(kg * 8 + u) * 512);
            #pragma unroll
            for (int half = 0; half < 2; ++half) {
                const bf16_t* x0 = Xs + (size_t)(half * 64 + l31) * XSTR + lh * 8;
                const bf16_t* x1 = x0 + 32 * XSTR;
                #pragma unroll
                for (int u = 0; u < 8; ++u) {
                    const int kc = kg * 8 + u;
                    bf16x8 bx0 = *(const bf16x8*)(x0 + kc * 16);
                    bf16x8 bx1 = *(const bf16x8*)(x1 + kc * 16);
                    acc[half][0] = __builtin_amdgcn_mfma_f32_32x32x16_bf16(af[u], bx0, acc[half][0], 0, 0, 0);
                    acc[half][1] = __builtin_amdgcn_mfma_f32_32x32x16_bf16(af[u], bx1, acc[half][1], 0, 0, 0);
                }
            }
        }
        const int e0 = wv * 32;
        #pragma unroll
        for (int half = 0; half < 2; ++half)
            #pragma unroll
            for (int z = 0; z < 2; ++z)
                #pragma unroll
                for (int g = 0; g < 4; ++g) {
                    const int e = e0 + 8 * g + 4 * lh;
                    #pragma unroll
                    for (int rr = 0; rr < 4; ++rr)
                        hreg[half][z][g][rr] = (bf16_t)(acc[half][z][4 * g + rr] + b2_s[e + rr]);
                }
    }
    __syncthreads();             // all waves done reading H

    {
        const int e0 = wv * 32;
        #pragma unroll
        for (int half = 0; half < 2; ++half)
            #pragma unroll
            for (int z = 0; z < 2; ++z) {
                const int n = half * 64 + z * 32 + l31;
                #pragma unroll
                for (int g = 0; g < 4; ++g)
                    *(bf16x4*)&Xs[(size_t)n * XSTR + e0 + 8 * g + 4 * lh] = hreg[half][z][g];
            }
    }
    __syncthreads();             // f now fully in Xs

    // ---- Phase 3: row norms ||f||^2  (512 threads: 4 per row) ----
    {
        const int r = t >> 2;
        const int q = t & 3;
        const bf16_t* frow = &Xs[(size_t)r * XSTR + q * 64];
        float s = 0.0f;
        #pragma unroll
        for (int c = 0; c < 8; ++c) {
            bf16x8 v = *(const bf16x8*)(frow + c * 8);
            #pragma unroll
            for (int u = 0; u < 8; ++u) { float f = (float)v[u]; s = fmaf(f, f, s); }
        }
        s += __shfl_xor(s, 1);
        s += __shfl_xor(s, 2);
        if (q == 0) nrm[r] = s;
    }
    __syncthreads();

    // ---- Phase 4: cdist (waves 0..3), C -> regs + global ----
    float cvv[16];
    int qbase = 0, mcol = 0;
    if (wv < 4) {
        const int qt = wv >> 1, rt = wv & 1;
        const bf16_t* qa = &Xs[(size_t)(qt * 32 + l31) * XSTR + lh * 8];
        const bf16_t* ra = &Xs[(size_t)(64 + rt * 32 + l31) * XSTR + lh * 8];
        f32x16 acc;
        #pragma unroll
        for (int i = 0; i < 16; ++i) acc[i] = 0.0f;
        #pragma unroll
        for (int kc = 0; kc < 16; ++kc) {
            bf16x8 av = *(const bf16x8*)(qa + kc * 16);
            bf16x8 bv = *(const bf16x8*)(ra + kc * 16);
            acc = __builtin_amdgcn_mfma_f32_32x32x16_bf16(av, bv, acc, 0, 0, 0);
        }
        mcol  = rt * 32 + l31;
        qbase = qt * 32;
        const float nr_m = nrm[64 + mcol];
        float* outC = out + 2048 + (size_t)2048 * 4096 + (size_t)b * 4096;
        #pragma unroll
        for (int g = 0; g < 4; ++g) {
            #pragma unroll
            for (int rr = 0; rr < 4; ++rr) {
                const int q = qbase + 8 * g + 4 * lh + rr;
                float d2 = nrm[q] + nr_m - 2.0f * acc[4 * g + rr];
                float cv = sqrtf(fmaxf(d2, 0.0f));
                cvv[4 * g + rr] = cv;
                outC[q * 64 + mcol] = cv;
            }
        }
    }
    __syncthreads();             // Fs dead everywhere; overlay Cs
    if (wv < 4) {
        #pragma unroll
        for (int g = 0; g < 4; ++g)
            #pragma unroll
            for (int rr = 0; rr < 4; ++rr)
                Cs[(qbase + 8 * g + 4 * lh + rr) * CSTR + mcol] = cvv[4 * g + rr];
    }
    __syncthreads();

    // ---- Phase 5: Sinkhorn (512 threads: 8 per row, 8 elems each) ----
    const int ki = t >> 3;      // 0..63
    const int jj = t & 7;       // strip of 8
    float rowV[8], colV[8];
    #pragma unroll
    for (int i = 0; i < 8; ++i) {
        const int m2 = jj * 8 + i;
        rowV[i] = fmaf(Cs[ki * CSTR + m2], -IEPS, lmr_s[m2]);
        colV[i] = fmaf(Cs[m2 * CSTR + ki], -IEPS, lmq_s[m2]);
    }
    const float lmq_k = lmq_s[ki];
    const float lmr_m = lmr_s[ki];

    for (int it = 0; it < NITER; ++it) {
        float mx = -1e30f;
        #pragma unroll
        for (int i = 0; i < 8; ++i) mx = fmaxf(mx, rowV[i] + lb_s[jj * 8 + i]);
        mx = fmaxf(mx, __shfl_xor(mx, 1));
        mx = fmaxf(mx, __shfl_xor(mx, 2));
        mx = fmaxf(mx, __shfl_xor(mx, 4));
        float s = 0.0f;
        #pragma unroll
        for (int i = 0; i < 8; ++i) s += __expf(rowV[i] + lb_s[jj * 8 + i] - mx);
        s += __shfl_xor(s, 1);
        s += __shfl_xor(s, 2);
        s += __shfl_xor(s, 4);
        if (jj == 0) la_s[ki] = -(lmq_k + mx + __logf(s));
        __syncthreads();

        mx = -1e30f;
        #pragma unroll
        for (int i = 0; i < 8; ++i) mx = fmaxf(mx, colV[i] + la_s[jj * 8 + i]);
        mx = fmaxf(mx, __shfl_xor(mx, 1));
        mx = fmaxf(mx, __shfl_xor(mx, 2));
        mx = fmaxf(mx, __shfl_xor(mx, 4));
        float s2 = 0.0f;
        #pragma unroll
        for (int i = 0; i < 8; ++i) s2 += __expf(colV[i] + la_s[jj * 8 + i] - mx);
        s2 += __shfl_xor(s2, 1);
        s2 += __shfl_xor(s2, 2);
        s2 += __shfl_xor(s2, 4);
        if (jj == 0) lb_s[ki] = -(lmr_m + mx + __logf(s2));
        __syncthreads();
    }

    // ---- Phase 6: T = exp(lK + la + lb) ----
    {
        const float base = lmq_k + la_s[ki];
        #pragma unroll
        for (int i = 0; i < 8; ++i) {
            const int m2 = jj * 8 + i;
            Ts[ki * CSTR + m2] = __expf(rowV[i] + lb_s[m2] + base);
        }
    }
    __syncthreads();

    // ---- Phase 7: power iterations ----
    for (int pi = 0; pi < MITER; ++pi) {
        float vv[8], rs = 0.0f;
        #pragma unroll
        for (int i = 0; i < 8; ++i) {
            float v = Ts[ki * CSTR + jj * 8 + i];
            v = v * v; vv[i] = v; rs += v;
        }
        rs += __shfl_xor(rs, 1); rs += __shfl_xor(rs, 2); rs += __shfl_xor(rs, 4);
        float inv = 1.0f / (rs + 1e-8f);
        #pragma unroll
        for (int i = 0; i < 8; ++i) Ts[ki * CSTR + jj * 8 + i] = vv[i] * inv;
        __syncthreads();

        float cs = 0.0f;
        #pragma unroll
        for (int i = 0; i < 8; ++i) { float v = Ts[(jj * 8 + i) * CSTR + ki]; vv[i] = v; cs += v; }
        cs += __shfl_xor(cs, 1); cs += __shfl_xor(cs, 2); cs += __shfl_xor(cs, 4);
        inv = 1.0f / (cs + 1e-8f);
        #pragma unroll
        for (int i = 0; i < 8; ++i) Ts[(jj * 8 + i) * CSTR + ki] = vv[i] * inv;
        __syncthreads();
    }

    // ---- Phase 8: write T, c = sum(T*C), sigmoid(-c) ----
    {
        float part = 0.0f;
        float tq[8];
        #pragma unroll
        for (int i = 0; i < 8; ++i) {
            const int m2 = jj * 8 + i;
            float tv = Ts[ki * CSTR + m2];
            tq[i] = tv;
            part = fmaf(tv, Cs[ki * CSTR + m2], part);
        }
        float* outT = out + 2048 + (size_t)b * 4096 + ki * 64 + jj * 8;
        ((float4*)outT)[0] = make_float4(tq[0], tq[1], tq[2], tq[3]);
        ((float4*)outT)[1] = make_float4(tq[4], tq[5], tq[6], tq[7]);
        #pragma unroll
        for (int off = 1; off < 64; off <<= 1) part += __shfl_xor(part, off);
        if (ln == 0) red_s[wv] = part;
    }
    __syncthreads();
    if (t == 0) {
        float c = 0.0f;
        #pragma unroll
        for (int w = 0; w < 8; ++w) c += red_s[w];
        out[2048 + (size_t)2 * 2048 * 4096 + b] = c;
        out[b] = 1.0f / (1.0f + __expf(c));
    }
}

extern "C" void kernel_launch(void* const* d_in, const int* in_sizes, int n_in,
                              void* d_out, int out_size, void* d_ws, size_t ws_size,
                              hipStream_t stream) {
    const float* sq = (const float*)d_in[0];
    const float* sr = (const float*)d_in[1];
    const float* mq = (const float*)d_in[2];
    const float* mr = (const float*)d_in[3];
    const float* W1 = (const float*)d_in[4];
    const float* b1 = (const float*)d_in[5];
    const float* W2 = (const float*)d_in[6];
    const float* b2 = (const float*)d_in[7];

    bf16_t* wf = (bf16_t*)d_ws;   // 131072 bf16 = 256 KB (ws is >=134 MB in practice)

    convert_w_frag<<<512, 256, 0, stream>>>(W1, W2, wf);
    sinkhorn_all<<<NB, 512, 0, stream>>>(sq, sr, mq, mr, b1, b2, wf, (float*)d_out);
}